// Round 10
// baseline (461.418 us; speedup 1.0000x reference)
//
#include <hip/hip_runtime.h>
#include <hip/hip_bf16.h>
#include <math.h>

#define CHANNELS 64
#define KK 25                   // 5x5 kernels
#define NBLK 26                 // 25 spline kernels + 1 root block
#define NCOL (NBLK * CHANNELS)  // 1664 columns of the fused GEMM
#define NTILES (NCOL / 16)      // 104 col-tiles of 16
#define ROWP 2560               // xk row stride: 5 d1-rows x 4 pairs x 128 B (pair-duplicated fp8)
#define GROUP_TILES 8
#define GROUP_BYTES (GROUP_TILES * 2048)  // 16 KB per staged group
#define NGROUPS (NTILES / GROUP_TILES)    // 13 (exact)
#define G_SPLIT 6               // L1 gemm split: groups [0,6) + [6,13)

typedef __attribute__((ext_vector_type(8))) short bf16x8;
typedef __attribute__((ext_vector_type(4))) float f32x4;
typedef __attribute__((ext_vector_type(2))) float f32x2;
typedef unsigned int u32;

// RNE float -> bf16 bits
__device__ __forceinline__ u32 f2bfu(float f) {
    u32 u = __float_as_uint(f);
    return (u + 0x7FFFu + ((u >> 16) & 1u)) >> 16;
}
__device__ __forceinline__ short f2bf(float f) { return (short)f2bfu(f); }

// async global->LDS, 16 B per lane (lds dest = wave-uniform base + lane*16)
__device__ __forceinline__ void async_copy16(const void* g, void* l) {
    __builtin_amdgcn_global_load_lds(
        (const __attribute__((address_space(1))) u32*)g,
        (__attribute__((address_space(3))) u32*)l, 16, 0, 0);
}

// ---------------- CSR scan kernels ----------------

__global__ __launch_bounds__(256) void scan_a(const u32* __restrict__ counts,
                                              u32* __restrict__ bsum, int N) {
    const int t = threadIdx.x;
    const int base = blockIdx.x * 1024 + t * 4;
    uint4 v = make_uint4(0, 0, 0, 0);
    if (base + 3 < N) v = *(const uint4*)(counts + base);
    else {
        if (base < N)     v.x = counts[base];
        if (base + 1 < N) v.y = counts[base + 1];
        if (base + 2 < N) v.z = counts[base + 2];
    }
    u32 s = v.x + v.y + v.z + v.w;
    for (int off = 32; off; off >>= 1) s += __shfl_down(s, off, 64);
    __shared__ u32 red[4];
    if ((t & 63) == 0) red[t >> 6] = s;
    __syncthreads();
    if (t == 0) bsum[blockIdx.x] = red[0] + red[1] + red[2] + red[3];
}

__global__ __launch_bounds__(64) void scan_b(u32* __restrict__ bsum, int nb) {
    const int lane = threadIdx.x;
    u32 run = 0;
    for (int base = 0; base < nb; base += 64) {
        u32 v = (base + lane < nb) ? bsum[base + lane] : 0u;
        const u32 orig = v;
        for (int off = 1; off < 64; off <<= 1) {
            u32 u = __shfl_up(v, off, 64);
            if (lane >= off) v += u;
        }
        if (base + lane < nb) bsum[base + lane] = run + v - orig;
        run += __shfl(v, 63, 64);
    }
}

__global__ __launch_bounds__(256) void scan_c(const u32* __restrict__ counts,
                                              const u32* __restrict__ bsum,
                                              u32* __restrict__ cursor, int N) {
    const int t = threadIdx.x;
    const int base = blockIdx.x * 1024 + t * 4;
    uint4 v = make_uint4(0, 0, 0, 0);
    if (base + 3 < N) v = *(const uint4*)(counts + base);
    else {
        if (base < N)     v.x = counts[base];
        if (base + 1 < N) v.y = counts[base + 1];
        if (base + 2 < N) v.z = counts[base + 2];
    }
    __shared__ u32 ps[256];
    ps[t] = v.x + v.y + v.z + v.w;
    __syncthreads();
    for (int off = 1; off < 256; off <<= 1) {
        u32 u = (t >= off) ? ps[t - off] : 0u;
        __syncthreads();
        ps[t] += u;
        __syncthreads();
    }
    u32 ex = ((t > 0) ? ps[t - 1] : 0u) + bsum[blockIdx.x];
    if (base < N)     cursor[base]     = ex;
    if (base + 1 < N) cursor[base + 1] = ex + v.x;
    if (base + 2 < N) cursor[base + 2] = ex + v.x + v.y;
    if (base + 3 < N) cursor[base + 3] = ex + v.x + v.y + v.z;
    if (base <= N - 1 && N - 1 <= base + 3)
        cursor[N] = ex + v.x + v.y + v.z + v.w;
}

// ---------------- gemm body (LDS-staged MFMA, R8-proven non-swapped form) ----------------

// Repack [W | root] fp32 -> Wb bf16 in B-fragment order.
// CELL-PERMUTED columns: within cell (t>>2), tile a = t&3 carries channels
// 4c + a (c = tile column 0..15). After the 4 MFMAs of a cell, lane m holds
// channels 4m..4m+3 across its four accumulators -> packed dword stores.
__global__ __launch_bounds__(256) void prep_w(const float* __restrict__ W,
                                              const float* __restrict__ root,
                                              __hip_bfloat16* __restrict__ Wb) {
    int idx = blockIdx.x * 256 + threadIdx.x;   // 104*2*64*8 = 106496
    if (idx >= NTILES * 2 * 64 * 8) return;
    int j = idx & 7;
    int l = (idx >> 3) & 63;
    int q = (idx >> 9) & 1;
    int t = idx >> 10;
    int cell = t >> 2;
    int o    = 4 * (l & 15) + (t & 3);          // channel within the 64-block
    int k    = q * 32 + (l >> 4) * 8 + j;
    float src = (cell < KK) ? W[cell * 4096 + k * 64 + o] : root[k * 64 + o];
    ((unsigned short*)Wb)[idx] = (unsigned short)f2bf(src);
}

// XK[n, c] = sum_i X[n,i] * B[i,c] over column groups [gr0, gr1).
// Spline cells (kc<25): fp8 e4m3 in PAIR-DUPLICATED layout — left slot of
// pair d0 (if d0<=3) and right slot of pair d0-1 (if d0>=1), one dword per
// lane per row. Root cell (kc==25): float4 into rootf[n*64 + 4m].
// Contains exactly (gr1-gr0) __syncthreads calls — wave-specialized callers
// must match that barrier count on the other path.
__device__ __forceinline__ void gemm_body(
    const float* __restrict__ X, const __hip_bfloat16* __restrict__ Wb,
    char* __restrict__ XK, float* __restrict__ rootf, int N, int gr0, int gr1)
{
    __shared__ __align__(16) char lds[2][GROUP_BYTES];
    const int lane = threadIdx.x & 63;
    const int wv   = threadIdx.x >> 6;          // 0..3 (only threads <256 enter)
    const int rb   = blockIdx.x * 64 + wv * 16;
    const int m    = lane & 15;
    const int quad = lane >> 4;

    const int rowc = min(rb + m, N - 1);
    const float* __restrict__ xp = X + (size_t)rowc * CHANNELS + quad * 8;
    float af[16];
    *(float4*)(af)      = *(const float4*)(xp);
    *(float4*)(af + 4)  = *(const float4*)(xp + 4);
    *(float4*)(af + 8)  = *(const float4*)(xp + 32);
    *(float4*)(af + 12) = *(const float4*)(xp + 36);
    bf16x8 A0, A1;
#pragma unroll
    for (int j = 0; j < 8; ++j) { A0[j] = f2bf(af[j]); A1[j] = f2bf(af[8 + j]); }

    const int r0 = rb + quad * 4;
    const int rmax = N - r0;
    char* __restrict__ orow0 = XK + (size_t)r0 * ROWP;

    const char* __restrict__ wbc = (const char*)Wb;
#define STAGE(g, buf)                                                          \
    {                                                                          \
        const char* gsrc = wbc + (size_t)(g) * GROUP_BYTES + wv * 4096 + lane * 16; \
        char* lbase = lds[buf] + wv * 4096;                                    \
        async_copy16(gsrc,        lbase);                                      \
        async_copy16(gsrc + 1024, lbase + 1024);                               \
        async_copy16(gsrc + 2048, lbase + 2048);                               \
        async_copy16(gsrc + 3072, lbase + 3072);                               \
    }

    STAGE(gr0, 0)
    for (int g = gr0; g < gr1; ++g) {
        const int li = (g - gr0) & 1;
        __syncthreads();           // drains staged loads for g
        if (g + 1 < gr1) STAGE(g + 1, li ^ 1)
        const char* lb = lds[li] + lane * 16;
#pragma unroll
        for (int cc = 0; cc < 2; ++cc) {       // 2 cells per group (8 tiles)
            const char* cb = lb + cc * 8192;
            f32x4 acc0 = {0.f, 0.f, 0.f, 0.f};
            f32x4 acc1 = {0.f, 0.f, 0.f, 0.f};
            f32x4 acc2 = {0.f, 0.f, 0.f, 0.f};
            f32x4 acc3 = {0.f, 0.f, 0.f, 0.f};
            acc0 = __builtin_amdgcn_mfma_f32_16x16x32_bf16(A0, *(const bf16x8*)(cb),        acc0, 0, 0, 0);
            acc0 = __builtin_amdgcn_mfma_f32_16x16x32_bf16(A1, *(const bf16x8*)(cb + 1024), acc0, 0, 0, 0);
            acc1 = __builtin_amdgcn_mfma_f32_16x16x32_bf16(A0, *(const bf16x8*)(cb + 2048), acc1, 0, 0, 0);
            acc1 = __builtin_amdgcn_mfma_f32_16x16x32_bf16(A1, *(const bf16x8*)(cb + 3072), acc1, 0, 0, 0);
            acc2 = __builtin_amdgcn_mfma_f32_16x16x32_bf16(A0, *(const bf16x8*)(cb + 4096), acc2, 0, 0, 0);
            acc2 = __builtin_amdgcn_mfma_f32_16x16x32_bf16(A1, *(const bf16x8*)(cb + 5120), acc2, 0, 0, 0);
            acc3 = __builtin_amdgcn_mfma_f32_16x16x32_bf16(A0, *(const bf16x8*)(cb + 6144), acc3, 0, 0, 0);
            acc3 = __builtin_amdgcn_mfma_f32_16x16x32_bf16(A1, *(const bf16x8*)(cb + 7168), acc3, 0, 0, 0);
            const int kc = g * 2 + cc;
            if (kc < KK) {
                const int d1 = kc / 5;          // lane-uniform
                const int d0 = kc - 5 * d1;
                const int boff = d1 * 512 + d0 * 128 + 4 * m;
#pragma unroll
                for (int i = 0; i < 4; ++i) {
                    if (i < rmax) {
                        u32 p = __builtin_amdgcn_cvt_pk_fp8_f32(acc0[i], acc1[i], 0u, false);
                        p = __builtin_amdgcn_cvt_pk_fp8_f32(acc2[i], acc3[i], p, true);
                        char* orow = orow0 + (size_t)i * ROWP;
                        if (d0 <= 3) *(u32*)(orow + boff) = p;        // left slot, pair d0
                        if (d0 >= 1) *(u32*)(orow + boff - 64) = p;   // right slot, pair d0-1
                    }
                }
            } else {
#pragma unroll
                for (int i = 0; i < 4; ++i) {
                    if (i < rmax) {
                        *(float4*)(rootf + (size_t)(r0 + i) * CHANNELS + 4 * m) =
                            make_float4(acc0[i], acc1[i], acc2[i], acc3[i]);
                    }
                }
            }
        }
    }
#undef STAGE
}

// fusedA (WAVE-SPECIALIZED, 512 threads): waves 0-3 run gemm groups [0,G_SPLIT)
// (6 barriers); waves 4-7 run the dst histogram with rank capture, edges in
// 6 barrier-matched chunks (strided, coalesced). Guarantees a 50/50 gemm/edge
// wave mix per CU and hides atomic latency under MFMA+stores.
__global__ __launch_bounds__(512) void gemm_hist(
    const float* __restrict__ X, const __hip_bfloat16* __restrict__ Wb,
    char* __restrict__ XK, float* __restrict__ rootf, int N,
    const int* __restrict__ ei, u32* __restrict__ counts,
    u32* __restrict__ rank, int E)
{
    if (threadIdx.x < 256) {
        gemm_body(X, Wb, XK, rootf, N, 0, G_SPLIT);   // 6 __syncthreads
    } else {
        const int tid = blockIdx.x * 256 + (threadIdx.x - 256);
        const int ET  = (int)gridDim.x * 256;
        const int rounds = (E + ET - 1) / ET;          // uniform
        int r = 0;
        for (int ch = 0; ch < G_SPLIT; ++ch) {
            const int rend = ((ch + 1) * rounds) / G_SPLIT;   // uniform
            for (; r < rend; ++r) {
                const int e = tid + r * ET;
                if (e < E) rank[e] = atomicAdd(&counts[ei[E + e]], 1u);
            }
            __syncthreads();                           // match gemm barrier ch
        }
    }
}

// Build one 8-B edge record: pair indices p0,p1 in [0,3], fracs f'=v-p in [0,1].
__device__ __forceinline__ uint2 mkrec(int src, float v0f, float v1f) {
    const float v0 = v0f * 4.0f, v1 = v1f * 4.0f;
    const int p0 = max(min((int)floorf(v0), 3), 0);
    const int p1 = max(min((int)floorf(v1), 3), 0);
    const float f0 = v0 - (float)p0;   // in [0,1]; ==1 only at the v=4 boundary
    const float f1 = v1 - (float)p1;
    const u32 f0q = min((u32)(f0 * 65536.0f), 65535u);
    const u32 f1q = min((u32)(f1 * 65536.0f), 65535u);
    uint2 rec;
    rec.x = (u32)src | ((u32)p0 << 16) | ((u32)p1 << 19);
    rec.y = f0q | (f1q << 16);
    return rec;
}

// fusedB (WAVE-SPECIALIZED, 512 threads): waves 0-3 run gemm groups
// [G_SPLIT,13) (7 barriers); waves 4-7 scatter 8-B edge records (atomic-free:
// cursor[dst] + rank[e]) in 7 barrier-matched chunks.
__global__ __launch_bounds__(512) void gemm_scatter(
    const float* __restrict__ X, const __hip_bfloat16* __restrict__ Wb,
    char* __restrict__ XK, float* __restrict__ rootf, int N,
    const int* __restrict__ ei, const float* __restrict__ ps,
    const u32* __restrict__ rank, const u32* __restrict__ cursor,
    uint2* __restrict__ sorted, int E)
{
    constexpr int NCH = NGROUPS - G_SPLIT;             // 7
    if (threadIdx.x < 256) {
        gemm_body(X, Wb, XK, rootf, N, G_SPLIT, NGROUPS);  // 7 __syncthreads
    } else {
        const int tid = blockIdx.x * 256 + (threadIdx.x - 256);
        const int ET  = (int)gridDim.x * 256;
        const int rounds = (E + ET - 1) / ET;          // uniform
        int r = 0;
        for (int ch = 0; ch < NCH; ++ch) {
            const int rend = ((ch + 1) * rounds) / NCH;       // uniform
            for (; r < rend; ++r) {
                const int e = tid + r * ET;
                if (e < E) {
                    const int dst = ei[E + e];
                    sorted[cursor[dst] + rank[e]] =
                        mkrec(ei[e], ps[2 * e], ps[2 * e + 1]);
                }
            }
            __syncthreads();                           // match gemm barrier ch
        }
    }
}

// plain full gemm (layer 2, 256 threads)
__global__ __launch_bounds__(256) void gemm_only(
    const float* __restrict__ X, const __hip_bfloat16* __restrict__ Wb,
    char* __restrict__ XK, float* __restrict__ rootf, int N)
{
    gemm_body(X, Wb, XK, rootf, N, 0, NGROUPS);
}

// ------------- unified agg: pair-layout fp8 gathers (2 full lines/edge) -------------
// Quarter q = lane>>4 handles edge i+q, sublane j = lane&15 handles channels
// 4j..4j+3. Gathers: (ll,hl) in one 128-B line at p1*512+p0*128, (lh,hh) in
// the line at +512. 4-deep record queue + 3-deep gather queue. Packed
// v_cvt_pk_f32_fp8 conversion. relu selects L1 (1) vs L2 (0) epilogue.
// Blocks >= node_blocks run prep_w for the NEXT layer's weights (W2 repack).
__global__ __launch_bounds__(256) void agg_node_p(
    const uint2* __restrict__ sorted, const u32* __restrict__ cursor,
    const char* __restrict__ XK, const float* __restrict__ rootf,
    const float* __restrict__ bias, float* __restrict__ out, int N, int relu,
    int node_blocks, const float* __restrict__ Wsrc,
    const float* __restrict__ rootsrc, __hip_bfloat16* __restrict__ Wbdst)
{
    if ((int)blockIdx.x >= node_blocks) {
        // fused prep_w for the next layer (runs only in the L1 agg dispatch)
        int idx = ((int)blockIdx.x - node_blocks) * 256 + threadIdx.x;
        if (idx < NTILES * 2 * 64 * 8) {
            int j = idx & 7;
            int l = (idx >> 3) & 63;
            int q = (idx >> 9) & 1;
            int t = idx >> 10;
            int cell = t >> 2;
            int o    = 4 * (l & 15) + (t & 3);
            int k    = q * 32 + (l >> 4) * 8 + j;
            float s = (cell < KK) ? Wsrc[cell * 4096 + k * 64 + o] : rootsrc[k * 64 + o];
            ((unsigned short*)Wbdst)[idx] = (unsigned short)f2bf(s);
        }
        return;
    }
    const int lane = threadIdx.x & 63;
    const int n = blockIdx.x * 4 + (threadIdx.x >> 6);
    if (n >= N) return;
    const int q = lane >> 4, j = lane & 15;
    const int beg = (int)cursor[n];
    const int end = (int)cursor[n + 1];

    float m0 = -INFINITY, m1 = -INFINITY, m2 = -INFINITY, m3 = -INFINITY;
    if (beg < end) {
        const int last = end - 1;
#define GATHP(r, gll, ghl, glh, ghh)                                           \
        {                                                                      \
            const char* b_ = XK + (size_t)((r).x & 0xffff) * ROWP + (j << 2);  \
            const int o_ = (((int)((r).x >> 16) & 7)                           \
                            + (((int)((r).x >> 19) & 7) << 2)) << 7;           \
            gll = *(const u32*)(b_ + o_);                                      \
            ghl = *(const u32*)(b_ + o_ + 64);                                 \
            glh = *(const u32*)(b_ + o_ + 512);                                \
            ghh = *(const u32*)(b_ + o_ + 576);                                \
        }
        uint2 rA = sorted[min(beg + q,      last)];
        uint2 rB = sorted[min(beg + 4 + q,  last)];
        uint2 rC = sorted[min(beg + 8 + q,  last)];
        u32 a0, a1, a2, a3, b0, b1, b2, b3, c0, c1, c2, c3;
        GATHP(rA, a0, a1, a2, a3)
        GATHP(rB, b0, b1, b2, b3)
        for (int i = beg; i < end; i += 4) {
            uint2 rD = sorted[min(i + 12 + q, last)];
            GATHP(rC, c0, c1, c2, c3)
            const float f0 = (float)(rA.y & 0xffff) * (1.0f / 65536.0f);
            const float f1 = (float)(rA.y >> 16)    * (1.0f / 65536.0f);
            const float w00 = (1.f - f0) * (1.f - f1);
            const float w10 = f0 * (1.f - f1);
            const float w01 = (1.f - f0) * f1;
            const float w11 = f0 * f1;
            f32x2 s01 = __builtin_amdgcn_cvt_pk_f32_fp8(a0, false) * w00
                      + __builtin_amdgcn_cvt_pk_f32_fp8(a1, false) * w10
                      + __builtin_amdgcn_cvt_pk_f32_fp8(a2, false) * w01
                      + __builtin_amdgcn_cvt_pk_f32_fp8(a3, false) * w11;
            f32x2 s23 = __builtin_amdgcn_cvt_pk_f32_fp8(a0, true)  * w00
                      + __builtin_amdgcn_cvt_pk_f32_fp8(a1, true)  * w10
                      + __builtin_amdgcn_cvt_pk_f32_fp8(a2, true)  * w01
                      + __builtin_amdgcn_cvt_pk_f32_fp8(a3, true)  * w11;
            m0 = fmaxf(m0, s01.x); m1 = fmaxf(m1, s01.y);
            m2 = fmaxf(m2, s23.x); m3 = fmaxf(m3, s23.y);
            rA = rB; rB = rC; rC = rD;
            a0 = b0; a1 = b1; a2 = b2; a3 = b3;
            b0 = c0; b1 = c1; b2 = c2; b3 = c3;
        }
#undef GATHP
    }
    m0 = fmaxf(m0, __shfl_xor(m0, 16, 64)); m0 = fmaxf(m0, __shfl_xor(m0, 32, 64));
    m1 = fmaxf(m1, __shfl_xor(m1, 16, 64)); m1 = fmaxf(m1, __shfl_xor(m1, 32, 64));
    m2 = fmaxf(m2, __shfl_xor(m2, 16, 64)); m2 = fmaxf(m2, __shfl_xor(m2, 32, 64));
    m3 = fmaxf(m3, __shfl_xor(m3, 16, 64)); m3 = fmaxf(m3, __shfl_xor(m3, 32, 64));
    const float a0 = isfinite(m0) ? m0 : 0.f;
    const float a1 = isfinite(m1) ? m1 : 0.f;
    const float a2 = isfinite(m2) ? m2 : 0.f;
    const float a3 = isfinite(m3) ? m3 : 0.f;

    const float4 rv = *(const float4*)(rootf + (size_t)n * CHANNELS + 4 * j);
    const float4 bv = *(const float4*)(bias + 4 * j);
    float r0 = a0 + rv.x + bv.x;
    float r1 = a1 + rv.y + bv.y;
    float r2 = a2 + rv.z + bv.z;
    float r3 = a3 + rv.w + bv.w;
    if (relu) {
        r0 = fmaxf(r0, 0.f); r1 = fmaxf(r1, 0.f);
        r2 = fmaxf(r2, 0.f); r3 = fmaxf(r3, 0.f);
    }
    if (q == 0)
        *(float4*)(out + (size_t)n * CHANNELS + 4 * j) = make_float4(r0, r1, r2, r3);
}

extern "C" void kernel_launch(void* const* d_in, const int* in_sizes, int n_in,
                              void* d_out, int out_size, void* d_ws, size_t ws_size,
                              hipStream_t stream) {
    const float* x     = (const float*)d_in[0];
    const int*   ei    = (const int*)d_in[1];
    const float* ps    = (const float*)d_in[2];
    const float* W1    = (const float*)d_in[3];
    const float* root1 = (const float*)d_in[4];
    const float* bias1 = (const float*)d_in[5];
    const float* W2    = (const float*)d_in[6];
    const float* root2 = (const float*)d_in[7];
    const float* bias2 = (const float*)d_in[8];
    float* out = (float*)d_out;

    const int N = in_sizes[0] / CHANNELS;
    const int E = in_sizes[1] / 2;

    // ---- workspace layout (~175 MB) ----
    char* ws = (char*)d_ws;
    char* xk = ws;                                                  // N*2560 fp8 pair-dup spline
    size_t off = (size_t)N * ROWP;
    float* h = (float*)(ws + off);                                  // 12.8 MB
    off += (size_t)N * CHANNELS * sizeof(float);
    float* rootf = (float*)(ws + off);                              // 12.8 MB (f32 root term)
    off += (size_t)N * CHANNELS * sizeof(float);
    uint2* sorted = (uint2*)(ws + off);                             // E*8 = 12.8 MB
    off += (size_t)E * sizeof(uint2);
    u32* rank = (u32*)(ws + off);                                   // E*4 = 6.4 MB
    off += (size_t)E * sizeof(u32);
    u32* counts = (u32*)(ws + off);                                 // N*4 (hist runs under gemm)
    off += (size_t)N * 4;
    __hip_bfloat16* Wb = (__hip_bfloat16*)(ws + off);               // 213 KB
    off += (size_t)NTILES * 2 * 64 * 8 * 2;
    u32* cursor = (u32*)(ws + off);                                 // (N+1)*4
    off += ((size_t)N + 1) * 4;
    u32* bsum = (u32*)(ws + off);                                   // ≤4 KB

    const int prep_blocks = (NTILES * 2 * 64 * 8 + 255) / 256;
    const int gemm_blocks = (N + 63) / 64;
    const int node_blocks = (N + 3) / 4;
    const int scan_blocks = (N + 1023) / 1024;

    // zero the histogram (capture-safe async memset)
    hipMemsetAsync(counts, 0, (size_t)N * 4, stream);
    prep_w<<<prep_blocks, 256, 0, stream>>>(W1, root1, Wb);

    // fusedA: L1 gemm groups [0,6) ∥ dst-histogram (wave-specialized, 512t)
    gemm_hist<<<gemm_blocks, 512, 0, stream>>>(
        x, Wb, xk, rootf, N, ei, counts, rank, E);

    scan_a<<<scan_blocks, 256, 0, stream>>>(counts, bsum, N);
    scan_b<<<1, 64, 0, stream>>>(bsum, scan_blocks);
    scan_c<<<scan_blocks, 256, 0, stream>>>(counts, bsum, cursor, N);

    // fusedB: L1 gemm groups [6,13) ∥ CSR scatter (wave-specialized, 512t)
    gemm_scatter<<<gemm_blocks, 512, 0, stream>>>(
        x, Wb, xk, rootf, N, ei, ps, rank, cursor, sorted, E);

    // L1 agg || fused prep_w(W2) repack
    agg_node_p<<<node_blocks + prep_blocks, 256, 0, stream>>>(
        sorted, cursor, xk, rootf, bias1, h, N, 1, node_blocks, W2, root2, Wb);

    // ---- layer 2 (pair-dup fp8 xk + f32 root, reuses sorted/cursor) ----
    gemm_only<<<gemm_blocks, 256, 0, stream>>>(h, Wb, xk, rootf, N);
    agg_node_p<<<node_blocks, 256, 0, stream>>>(
        sorted, cursor, xk, rootf, bias2, out, N, 0, node_blocks, W2, root2, Wb);
}

// Round 11
// 413.734 us; speedup vs baseline: 1.1153x; 1.1153x over previous
//
#include <hip/hip_runtime.h>
#include <hip/hip_bf16.h>
#include <math.h>

#define CHANNELS 64
#define KK 25                   // 5x5 kernels
#define NBLK 26                 // 25 spline kernels + 1 root block
#define NCOL (NBLK * CHANNELS)  // 1664 columns of the fused GEMM
#define NTILES (NCOL / 16)      // 104 col-tiles of 16
#define ROWP 2560               // xk row stride: 5 d1-rows x 4 pairs x 128 B (interleaved pair-dup fp8)
#define CELL_BYTES 8192         // one cell = 4 tiles x 2 KB

typedef __attribute__((ext_vector_type(8))) short bf16x8;
typedef __attribute__((ext_vector_type(4))) float f32x4;
typedef __attribute__((ext_vector_type(2))) float f32x2;
typedef unsigned int u32;

// RNE float -> bf16 bits
__device__ __forceinline__ u32 f2bfu(float f) {
    u32 u = __float_as_uint(f);
    return (u + 0x7FFFu + ((u >> 16) & 1u)) >> 16;
}
__device__ __forceinline__ short f2bf(float f) { return (short)f2bfu(f); }

// async global->LDS, 16 B per lane (lds dest = wave-uniform base + lane*16)
__device__ __forceinline__ void async_copy16(const void* g, void* l) {
    __builtin_amdgcn_global_load_lds(
        (const __attribute__((address_space(1))) u32*)g,
        (__attribute__((address_space(3))) u32*)l, 16, 0, 0);
}

// compile-time unroll helper
template<int N> struct IC { static constexpr int v = N; };
template<int G, int GEND, class F>
__device__ __forceinline__ void unrollg(F f) {
    if constexpr (G < GEND) { f(IC<G>{}); unrollg<G + 1, GEND>(f); }
}

// epilogue stores issued per cell (uint2 pair stores; root cell = 4 float4)
__device__ constexpr int cell_stores(int c) {
    return (c < KK) ? (((c % 5) != 0) ? 4 : 0) : 4;
}

// ---------------- CSR scan kernels ----------------

__global__ __launch_bounds__(256) void scan_a(const u32* __restrict__ counts,
                                              u32* __restrict__ bsum, int N) {
    const int t = threadIdx.x;
    const int base = blockIdx.x * 1024 + t * 4;
    uint4 v = make_uint4(0, 0, 0, 0);
    if (base + 3 < N) v = *(const uint4*)(counts + base);
    else {
        if (base < N)     v.x = counts[base];
        if (base + 1 < N) v.y = counts[base + 1];
        if (base + 2 < N) v.z = counts[base + 2];
    }
    u32 s = v.x + v.y + v.z + v.w;
    for (int off = 32; off; off >>= 1) s += __shfl_down(s, off, 64);
    __shared__ u32 red[4];
    if ((t & 63) == 0) red[t >> 6] = s;
    __syncthreads();
    if (t == 0) bsum[blockIdx.x] = red[0] + red[1] + red[2] + red[3];
}

__global__ __launch_bounds__(64) void scan_b(u32* __restrict__ bsum, int nb) {
    const int lane = threadIdx.x;
    u32 run = 0;
    for (int base = 0; base < nb; base += 64) {
        u32 v = (base + lane < nb) ? bsum[base + lane] : 0u;
        const u32 orig = v;
        for (int off = 1; off < 64; off <<= 1) {
            u32 u = __shfl_up(v, off, 64);
            if (lane >= off) v += u;
        }
        if (base + lane < nb) bsum[base + lane] = run + v - orig;
        run += __shfl(v, 63, 64);
    }
}

__global__ __launch_bounds__(256) void scan_c(const u32* __restrict__ counts,
                                              const u32* __restrict__ bsum,
                                              u32* __restrict__ cursor, int N) {
    const int t = threadIdx.x;
    const int base = blockIdx.x * 1024 + t * 4;
    uint4 v = make_uint4(0, 0, 0, 0);
    if (base + 3 < N) v = *(const uint4*)(counts + base);
    else {
        if (base < N)     v.x = counts[base];
        if (base + 1 < N) v.y = counts[base + 1];
        if (base + 2 < N) v.z = counts[base + 2];
    }
    __shared__ u32 ps[256];
    ps[t] = v.x + v.y + v.z + v.w;
    __syncthreads();
    for (int off = 1; off < 256; off <<= 1) {
        u32 u = (t >= off) ? ps[t - off] : 0u;
        __syncthreads();
        ps[t] += u;
        __syncthreads();
    }
    u32 ex = ((t > 0) ? ps[t - 1] : 0u) + bsum[blockIdx.x];
    if (base < N)     cursor[base]     = ex;
    if (base + 1 < N) cursor[base + 1] = ex + v.x;
    if (base + 2 < N) cursor[base + 2] = ex + v.x + v.y;
    if (base + 3 < N) cursor[base + 3] = ex + v.x + v.y + v.z;
    if (base <= N - 1 && N - 1 <= base + 3)
        cursor[N] = ex + v.x + v.y + v.z + v.w;
}

// standalone dst histogram with rank capture, 4 edges/thread (atomic MLP).
__global__ __launch_bounds__(256) void hist_edges(const int* __restrict__ ei,
                                                  u32* __restrict__ counts,
                                                  u32* __restrict__ rank, int E) {
    const int e0 = blockIdx.x * 1024 + threadIdx.x * 4;
    if (e0 + 3 < E) {
        const int4 d = *(const int4*)(ei + E + e0);
        const u32 r0 = atomicAdd(&counts[d.x], 1u);
        const u32 r1 = atomicAdd(&counts[d.y], 1u);
        const u32 r2 = atomicAdd(&counts[d.z], 1u);
        const u32 r3 = atomicAdd(&counts[d.w], 1u);
        *(uint4*)(rank + e0) = make_uint4(r0, r1, r2, r3);
    } else {
        for (int k = 0; k < 4; ++k)
            if (e0 + k < E)
                rank[e0 + k] = atomicAdd(&counts[ei[E + e0 + k]], 1u);
    }
}

// ---------------- weight repack ----------------

// Repack [W | root] fp32 -> Wb bf16 in B-fragment order.
// CELL-PERMUTED columns: within cell (t>>2), tile a = t&3 carries channels
// 4c + a (c = tile column 0..15). After the 4 MFMAs of a cell, lane m holds
// channels 4m..4m+3 across its four accumulators -> packed dword stores.
__global__ __launch_bounds__(256) void prep_w(const float* __restrict__ W,
                                              const float* __restrict__ root,
                                              __hip_bfloat16* __restrict__ Wb) {
    int idx = blockIdx.x * 256 + threadIdx.x;   // 104*2*64*8 = 106496
    if (idx >= NTILES * 2 * 64 * 8) return;
    int j = idx & 7;
    int l = (idx >> 3) & 63;
    int q = (idx >> 9) & 1;
    int t = idx >> 10;
    int cell = t >> 2;
    int o    = 4 * (l & 15) + (t & 3);          // channel within the 64-block
    int k    = q * 32 + (l >> 4) * 8 + j;
    float src = (cell < KK) ? W[cell * 4096 + k * 64 + o] : root[k * 64 + o];
    ((unsigned short*)Wb)[idx] = (unsigned short)f2bf(src);
}

// ---------------- BARRIER-FREE gemm (wave-private staging) ----------------
// Each wave owns 16 output rows and its OWN double-buffered LDS (2 x 8 KB =
// one cell each). No __syncthreads anywhere: per-wave counted vmcnt orders
// staged loads; epilogue stores are NEVER drained (up to S+8 VMEM ops stay
// in flight continuously). LDS = 4 waves x 16 KB = 64 KB -> 2 blocks/CU.
// Interleaved pair lines (R7-proven): line (p,d1) at d1*512 + p*128 holds
// dwords [L0 R0 L1 R1 ...]; cell d0>=1 stores uint2 {prev,cur} at pair d0-1,
// offset 8m. Root cell -> float4 into rootf. OOB rows clamp to N-1 and
// ALWAYS store (same-value writes) so vmcnt constants stay valid per wave.
__global__ __launch_bounds__(256) void gemm_nb(
    const float* __restrict__ X, const __hip_bfloat16* __restrict__ Wb,
    char* __restrict__ XK, float* __restrict__ rootf, int N)
{
    __shared__ __align__(16) char lds[4][2][CELL_BYTES];
    const int lane = threadIdx.x & 63;
    const int wv   = threadIdx.x >> 6;
    const int rb   = blockIdx.x * 64 + wv * 16;
    const int m    = lane & 15;
    const int quad = lane >> 4;
    const int Nm1  = N - 1;

    const int rowc = min(rb + m, Nm1);
    const float* __restrict__ xp = X + (size_t)rowc * CHANNELS + quad * 8;
    float af[16];
    *(float4*)(af)      = *(const float4*)(xp);
    *(float4*)(af + 4)  = *(const float4*)(xp + 4);
    *(float4*)(af + 8)  = *(const float4*)(xp + 32);
    *(float4*)(af + 12) = *(const float4*)(xp + 36);
    bf16x8 A0, A1;
#pragma unroll
    for (int j = 0; j < 8; ++j) { A0[j] = f2bf(af[j]); A1[j] = f2bf(af[8 + j]); }

    const int r0 = rb + quad * 4;
    const char* __restrict__ wbc = (const char*)Wb;
    char* const ldsw = &lds[wv][0][0];

    auto stage = [&](int c, int buf) {
        const char* gsrc = wbc + (size_t)c * CELL_BYTES + lane * 16;
        char* lb = ldsw + buf * CELL_BYTES;
#pragma unroll
        for (int k = 0; k < 8; ++k)
            async_copy16(gsrc + k * 1024, lb + k * 1024);
    };

    u32 prevp[4] = {0u, 0u, 0u, 0u};   // pending left-slot dwords (per row i)

    stage(0, 0);
    stage(1, 1);

    unrollg<0, NBLK>([&](auto icc) {
        constexpr int c = decltype(icc)::v;
        // wait for stage(c): allow everything issued after it to remain
        // in flight = stores(c-1) + (stage(c+1) if it exists).
        constexpr int NC = (c == 0) ? 8
                         : cell_stores(c - 1) + ((c + 1 < NBLK) ? 8 : 0);
        asm volatile("s_waitcnt vmcnt(%0)" :: "i"(NC) : "memory");

        const char* cb = ldsw + (c & 1) * CELL_BYTES + lane * 16;
        f32x4 acc0 = {0.f, 0.f, 0.f, 0.f};
        f32x4 acc1 = {0.f, 0.f, 0.f, 0.f};
        f32x4 acc2 = {0.f, 0.f, 0.f, 0.f};
        f32x4 acc3 = {0.f, 0.f, 0.f, 0.f};
        acc0 = __builtin_amdgcn_mfma_f32_16x16x32_bf16(A0, *(const bf16x8*)(cb),        acc0, 0, 0, 0);
        acc0 = __builtin_amdgcn_mfma_f32_16x16x32_bf16(A1, *(const bf16x8*)(cb + 1024), acc0, 0, 0, 0);
        acc1 = __builtin_amdgcn_mfma_f32_16x16x32_bf16(A0, *(const bf16x8*)(cb + 2048), acc1, 0, 0, 0);
        acc1 = __builtin_amdgcn_mfma_f32_16x16x32_bf16(A1, *(const bf16x8*)(cb + 3072), acc1, 0, 0, 0);
        acc2 = __builtin_amdgcn_mfma_f32_16x16x32_bf16(A0, *(const bf16x8*)(cb + 4096), acc2, 0, 0, 0);
        acc2 = __builtin_amdgcn_mfma_f32_16x16x32_bf16(A1, *(const bf16x8*)(cb + 5120), acc2, 0, 0, 0);
        acc3 = __builtin_amdgcn_mfma_f32_16x16x32_bf16(A0, *(const bf16x8*)(cb + 6144), acc3, 0, 0, 0);
        acc3 = __builtin_amdgcn_mfma_f32_16x16x32_bf16(A1, *(const bf16x8*)(cb + 7168), acc3, 0, 0, 0);

        if constexpr (c < KK) {
            constexpr int d1 = c / 5;
            constexpr int d0 = c % 5;
            u32 pk[4];
#pragma unroll
            for (int i = 0; i < 4; ++i) {
                u32 p = __builtin_amdgcn_cvt_pk_fp8_f32(acc0[i], acc1[i], 0u, false);
                p = __builtin_amdgcn_cvt_pk_fp8_f32(acc2[i], acc3[i], p, true);
                pk[i] = p;
            }
            if constexpr (d0 >= 1) {
#pragma unroll
                for (int i = 0; i < 4; ++i) {
                    const int r = min(r0 + i, Nm1);
                    *(uint2*)(XK + (size_t)r * ROWP
                              + (d1 * 512 + (d0 - 1) * 128) + 8 * m) =
                        make_uint2(prevp[i], pk[i]);
                }
            }
#pragma unroll
            for (int i = 0; i < 4; ++i) prevp[i] = pk[i];
        } else {
#pragma unroll
            for (int i = 0; i < 4; ++i) {
                const int r = min(r0 + i, Nm1);
                *(float4*)(rootf + (size_t)r * CHANNELS + 4 * m) =
                    make_float4(acc0[i], acc1[i], acc2[i], acc3[i]);
            }
        }
        if constexpr (c + 2 < NBLK) {
            // ds_reads of this cell are long since complete; make it explicit
            asm volatile("s_waitcnt lgkmcnt(0)" ::: "memory");
            stage(c + 2, c & 1);       // refill the buffer just consumed
        }
    });
}

// Build one 8-B edge record: pair indices p0,p1 in [0,3], fracs f'=v-p in [0,1].
__device__ __forceinline__ uint2 mkrec(int src, float v0f, float v1f) {
    const float v0 = v0f * 4.0f, v1 = v1f * 4.0f;
    const int p0 = max(min((int)floorf(v0), 3), 0);
    const int p1 = max(min((int)floorf(v1), 3), 0);
    const float f0 = v0 - (float)p0;   // in [0,1]; ==1 only at the v=4 boundary
    const float f1 = v1 - (float)p1;
    const u32 f0q = min((u32)(f0 * 65536.0f), 65535u);
    const u32 f1q = min((u32)(f1 * 65536.0f), 65535u);
    uint2 rec;
    rec.x = (u32)src | ((u32)p0 << 16) | ((u32)p1 << 19);
    rec.y = f0q | (f1q << 16);
    return rec;
}

// standalone CSR scatter (atomic-free: cursor[dst] + rank[e]), 4 edges/thread.
__global__ __launch_bounds__(256) void edge_scatter(
    const int* __restrict__ ei, const float* __restrict__ ps,
    const u32* __restrict__ rank, const u32* __restrict__ cursor,
    uint2* __restrict__ sorted, int E)
{
    const int e0 = blockIdx.x * 1024 + threadIdx.x * 4;
    if (e0 + 3 < E) {
        const int4 s  = *(const int4*)(ei + e0);
        const int4 d  = *(const int4*)(ei + E + e0);
        const float4 pa = *(const float4*)(ps + 2 * e0);
        const float4 pb = *(const float4*)(ps + 2 * e0 + 4);
        const uint4 rk = *(const uint4*)(rank + e0);
        const u32 c0 = cursor[d.x];
        const u32 c1 = cursor[d.y];
        const u32 c2 = cursor[d.z];
        const u32 c3 = cursor[d.w];
        sorted[c0 + rk.x] = mkrec(s.x, pa.x, pa.y);
        sorted[c1 + rk.y] = mkrec(s.y, pa.z, pa.w);
        sorted[c2 + rk.z] = mkrec(s.z, pb.x, pb.y);
        sorted[c3 + rk.w] = mkrec(s.w, pb.z, pb.w);
    } else {
        for (int k = 0; k < 4; ++k) {
            const int e = e0 + k;
            if (e < E)
                sorted[cursor[ei[E + e]] + rank[e]] =
                    mkrec(ei[e], ps[2 * e], ps[2 * e + 1]);
        }
    }
}

// ------------- unified agg: interleaved pair lines, 2 uint2 gathers/edge -------------
// (R7-proven format.) Quarter q = lane>>4 handles edge i+q, sublane j =
// lane&15 handles channels 4j..4j+3. Line (p0,p1) at p1*512+p0*128: dword
// 2j = left cell, 2j+1 = right cell -> one uint2 at +8j; second line at
// +512. 4-deep record queue + 3-deep gather queue. relu selects L1/L2
// epilogue. Blocks >= node_blocks run prep_w for the NEXT layer's weights.
__global__ __launch_bounds__(256) void agg_node_p(
    const uint2* __restrict__ sorted, const u32* __restrict__ cursor,
    const char* __restrict__ XK, const float* __restrict__ rootf,
    const float* __restrict__ bias, float* __restrict__ out, int N, int relu,
    int node_blocks, const float* __restrict__ Wsrc,
    const float* __restrict__ rootsrc, __hip_bfloat16* __restrict__ Wbdst)
{
    if ((int)blockIdx.x >= node_blocks) {
        // fused prep_w for the next layer (runs only in the L1 agg dispatch)
        int idx = ((int)blockIdx.x - node_blocks) * 256 + threadIdx.x;
        if (idx < NTILES * 2 * 64 * 8) {
            int j = idx & 7;
            int l = (idx >> 3) & 63;
            int q = (idx >> 9) & 1;
            int t = idx >> 10;
            int cell = t >> 2;
            int o    = 4 * (l & 15) + (t & 3);
            int k    = q * 32 + (l >> 4) * 8 + j;
            float s = (cell < KK) ? Wsrc[cell * 4096 + k * 64 + o] : rootsrc[k * 64 + o];
            ((unsigned short*)Wbdst)[idx] = (unsigned short)f2bf(s);
        }
        return;
    }
    const int lane = threadIdx.x & 63;
    const int n = blockIdx.x * 4 + (threadIdx.x >> 6);
    if (n >= N) return;
    const int q = lane >> 4, j = lane & 15;
    const int beg = (int)cursor[n];
    const int end = (int)cursor[n + 1];

    float m0 = -INFINITY, m1 = -INFINITY, m2 = -INFINITY, m3 = -INFINITY;
    if (beg < end) {
        const int last = end - 1;
#define GATHP(r, q0, q1)                                                       \
        {                                                                      \
            const char* b_ = XK + (size_t)((r).x & 0xffff) * ROWP + (j << 3);  \
            const int o_ = (((int)((r).x >> 16) & 7)                           \
                            + (((int)((r).x >> 19) & 7) << 2)) << 7;           \
            q0 = *(const uint2*)(b_ + o_);                                     \
            q1 = *(const uint2*)(b_ + o_ + 512);                               \
        }
        uint2 rA = sorted[min(beg + q,      last)];
        uint2 rB = sorted[min(beg + 4 + q,  last)];
        uint2 rC = sorted[min(beg + 8 + q,  last)];
        uint2 ga0, ga1, gb0, gb1, gc0, gc1;
        GATHP(rA, ga0, ga1)
        GATHP(rB, gb0, gb1)
        for (int i = beg; i < end; i += 4) {
            uint2 rD = sorted[min(i + 12 + q, last)];
            GATHP(rC, gc0, gc1)
            const float f0 = (float)(rA.y & 0xffff) * (1.0f / 65536.0f);
            const float f1 = (float)(rA.y >> 16)    * (1.0f / 65536.0f);
            const float w00 = (1.f - f0) * (1.f - f1);
            const float w10 = f0 * (1.f - f1);
            const float w01 = (1.f - f0) * f1;
            const float w11 = f0 * f1;
            f32x2 s01 = __builtin_amdgcn_cvt_pk_f32_fp8(ga0.x, false) * w00
                      + __builtin_amdgcn_cvt_pk_f32_fp8(ga0.y, false) * w10
                      + __builtin_amdgcn_cvt_pk_f32_fp8(ga1.x, false) * w01
                      + __builtin_amdgcn_cvt_pk_f32_fp8(ga1.y, false) * w11;
            f32x2 s23 = __builtin_amdgcn_cvt_pk_f32_fp8(ga0.x, true)  * w00
                      + __builtin_amdgcn_cvt_pk_f32_fp8(ga0.y, true)  * w10
                      + __builtin_amdgcn_cvt_pk_f32_fp8(ga1.x, true)  * w01
                      + __builtin_amdgcn_cvt_pk_f32_fp8(ga1.y, true)  * w11;
            m0 = fmaxf(m0, s01.x); m1 = fmaxf(m1, s01.y);
            m2 = fmaxf(m2, s23.x); m3 = fmaxf(m3, s23.y);
            rA = rB; rB = rC; rC = rD;
            ga0 = gb0; ga1 = gb1;
            gb0 = gc0; gb1 = gc1;
        }
#undef GATHP
    }
    m0 = fmaxf(m0, __shfl_xor(m0, 16, 64)); m0 = fmaxf(m0, __shfl_xor(m0, 32, 64));
    m1 = fmaxf(m1, __shfl_xor(m1, 16, 64)); m1 = fmaxf(m1, __shfl_xor(m1, 32, 64));
    m2 = fmaxf(m2, __shfl_xor(m2, 16, 64)); m2 = fmaxf(m2, __shfl_xor(m2, 32, 64));
    m3 = fmaxf(m3, __shfl_xor(m3, 16, 64)); m3 = fmaxf(m3, __shfl_xor(m3, 32, 64));
    const float a0 = isfinite(m0) ? m0 : 0.f;
    const float a1 = isfinite(m1) ? m1 : 0.f;
    const float a2 = isfinite(m2) ? m2 : 0.f;
    const float a3 = isfinite(m3) ? m3 : 0.f;

    const float4 rv = *(const float4*)(rootf + (size_t)n * CHANNELS + 4 * j);
    const float4 bv = *(const float4*)(bias + 4 * j);
    float r0 = a0 + rv.x + bv.x;
    float r1 = a1 + rv.y + bv.y;
    float r2 = a2 + rv.z + bv.z;
    float r3 = a3 + rv.w + bv.w;
    if (relu) {
        r0 = fmaxf(r0, 0.f); r1 = fmaxf(r1, 0.f);
        r2 = fmaxf(r2, 0.f); r3 = fmaxf(r3, 0.f);
    }
    if (q == 0)
        *(float4*)(out + (size_t)n * CHANNELS + 4 * j) = make_float4(r0, r1, r2, r3);
}

extern "C" void kernel_launch(void* const* d_in, const int* in_sizes, int n_in,
                              void* d_out, int out_size, void* d_ws, size_t ws_size,
                              hipStream_t stream) {
    const float* x     = (const float*)d_in[0];
    const int*   ei    = (const int*)d_in[1];
    const float* ps    = (const float*)d_in[2];
    const float* W1    = (const float*)d_in[3];
    const float* root1 = (const float*)d_in[4];
    const float* bias1 = (const float*)d_in[5];
    const float* W2    = (const float*)d_in[6];
    const float* root2 = (const float*)d_in[7];
    const float* bias2 = (const float*)d_in[8];
    float* out = (float*)d_out;

    const int N = in_sizes[0] / CHANNELS;
    const int E = in_sizes[1] / 2;

    // ---- workspace layout (~175 MB) ----
    char* ws = (char*)d_ws;
    char* xk = ws;                                                  // N*2560 fp8 pair-dup spline
    size_t off = (size_t)N * ROWP;
    float* h = (float*)(ws + off);                                  // 12.8 MB
    off += (size_t)N * CHANNELS * sizeof(float);
    float* rootf = (float*)(ws + off);                              // 12.8 MB (f32 root term)
    off += (size_t)N * CHANNELS * sizeof(float);
    uint2* sorted = (uint2*)(ws + off);                             // E*8 = 12.8 MB
    off += (size_t)E * sizeof(uint2);
    u32* rank = (u32*)(ws + off);                                   // E*4 = 6.4 MB
    off += (size_t)E * sizeof(u32);
    u32* counts = (u32*)(ws + off);                                 // N*4
    off += (size_t)N * 4;
    __hip_bfloat16* Wb = (__hip_bfloat16*)(ws + off);               // 213 KB
    off += (size_t)NTILES * 2 * 64 * 8 * 2;
    u32* cursor = (u32*)(ws + off);                                 // (N+1)*4
    off += ((size_t)N + 1) * 4;
    u32* bsum = (u32*)(ws + off);                                   // ≤4 KB

    const int prep_blocks = (NTILES * 2 * 64 * 8 + 255) / 256;
    const int gemm_blocks = (N + 63) / 64;
    const int node_blocks = (N + 3) / 4;
    const int edgeQ_blocks = (E + 1023) / 1024;
    const int scan_blocks = (N + 1023) / 1024;

    // zero the histogram (capture-safe async memset)
    hipMemsetAsync(counts, 0, (size_t)N * 4, stream);
    prep_w<<<prep_blocks, 256, 0, stream>>>(W1, root1, Wb);

    // dst histogram with rank capture (standalone, 4 edges/thread)
    hist_edges<<<edgeQ_blocks, 256, 0, stream>>>(ei, counts, rank, E);

    // L1 gemm — barrier-free wave-private pipeline
    gemm_nb<<<gemm_blocks, 256, 0, stream>>>(x, Wb, xk, rootf, N);

    scan_a<<<scan_blocks, 256, 0, stream>>>(counts, bsum, N);
    scan_b<<<1, 64, 0, stream>>>(bsum, scan_blocks);
    scan_c<<<scan_blocks, 256, 0, stream>>>(counts, bsum, cursor, N);

    // CSR scatter (atomic-free, standalone, 4 edges/thread)
    edge_scatter<<<edgeQ_blocks, 256, 0, stream>>>(ei, ps, rank, cursor, sorted, E);

    // L1 agg || fused prep_w(W2) repack
    agg_node_p<<<node_blocks + prep_blocks, 256, 0, stream>>>(
        sorted, cursor, xk, rootf, bias1, h, N, 1, node_blocks, W2, root2, Wb);

    // ---- layer 2 (reuses sorted/cursor) ----
    gemm_nb<<<gemm_blocks, 256, 0, stream>>>(h, Wb, xk, rootf, N);
    agg_node_p<<<node_blocks, 256, 0, stream>>>(
        sorted, cursor, xk, rootf, bias2, out, N, 0, node_blocks, W2, root2, Wb);
}

// Round 13
// 366.306 us; speedup vs baseline: 1.2597x; 1.1295x over previous
//
#include <hip/hip_runtime.h>
#include <hip/hip_bf16.h>
#include <math.h>

#define CHANNELS 64
#define KK 25                   // 5x5 kernels
#define NBLK 26                 // 25 spline kernels + 1 root block
#define NCOL (NBLK * CHANNELS)  // 1664 columns of the fused GEMM
#define NTILES (NCOL / 16)      // 104 col-tiles of 16
#define ROWP 2560               // xk row stride: 5 d1-rows x 4 pairs x 128 B (interleaved pair-dup fp8)
#define CELL_BYTES 8192         // one cell = 4 tiles x 2 KB

// ---- bucket-sort CSR parameters ----
#define BK_SHIFT 7
#define BK_W 128                // dst values per bucket
#define BK_CAP 5120             // record capacity per bucket (mean ~4092, +16 sigma)
#define BK_MAXNB 512            // max buckets supported (N <= 65536)
#define EDGES_PER_BLK 4096      // bucket_scatter edges per block

typedef __attribute__((ext_vector_type(8))) short bf16x8;
typedef __attribute__((ext_vector_type(4))) float f32x4;
typedef __attribute__((ext_vector_type(2))) float f32x2;
typedef unsigned int u32;

// RNE float -> bf16 bits
__device__ __forceinline__ u32 f2bfu(float f) {
    u32 u = __float_as_uint(f);
    return (u + 0x7FFFu + ((u >> 16) & 1u)) >> 16;
}
__device__ __forceinline__ short f2bf(float f) { return (short)f2bfu(f); }

// async global->LDS, 16 B per lane (lds dest = wave-uniform base + lane*16)
__device__ __forceinline__ void async_copy16(const void* g, void* l) {
    __builtin_amdgcn_global_load_lds(
        (const __attribute__((address_space(1))) u32*)g,
        (__attribute__((address_space(3))) u32*)l, 16, 0, 0);
}

// compile-time unroll helper
template<int N> struct IC { static constexpr int v = N; };
template<int G, int GEND, class F>
__device__ __forceinline__ void unrollg(F f) {
    if constexpr (G < GEND) { f(IC<G>{}); unrollg<G + 1, GEND>(f); }
}

// epilogue stores issued per cell (uint2 pair stores; root cell = 4 float4)
__device__ constexpr int cell_stores(int c) {
    return (c < KK) ? (((c % 5) != 0) ? 4 : 0) : 4;
}

// ---------------- weight repack ----------------

// Repack [W | root] fp32 -> Wb bf16 in B-fragment order.
// CELL-PERMUTED columns: within cell (t>>2), tile a = t&3 carries channels
// 4c + a (c = tile column 0..15). After the 4 MFMAs of a cell, lane m holds
// channels 4m..4m+3 across its four accumulators -> packed dword stores.
__global__ __launch_bounds__(256) void prep_w(const float* __restrict__ W,
                                              const float* __restrict__ root,
                                              __hip_bfloat16* __restrict__ Wb) {
    int idx = blockIdx.x * 256 + threadIdx.x;   // 104*2*64*8 = 106496
    if (idx >= NTILES * 2 * 64 * 8) return;
    int j = idx & 7;
    int l = (idx >> 3) & 63;
    int q = (idx >> 9) & 1;
    int t = idx >> 10;
    int cell = t >> 2;
    int o    = 4 * (l & 15) + (t & 3);          // channel within the 64-block
    int k    = q * 32 + (l >> 4) * 8 + j;
    float src = (cell < KK) ? W[cell * 4096 + k * 64 + o] : root[k * 64 + o];
    ((unsigned short*)Wb)[idx] = (unsigned short)f2bf(src);
}

// Build one 8-B edge record: pair indices p0,p1 in [0,3], fracs f'=v-p in [0,1].
__device__ __forceinline__ uint2 mkrec(int src, float v0f, float v1f) {
    const float v0 = v0f * 4.0f, v1 = v1f * 4.0f;
    const int p0 = max(min((int)floorf(v0), 3), 0);
    const int p1 = max(min((int)floorf(v1), 3), 0);
    const float f0 = v0 - (float)p0;   // in [0,1]; ==1 only at the v=4 boundary
    const float f1 = v1 - (float)p1;
    const u32 f0q = min((u32)(f0 * 65536.0f), 65535u);
    const u32 f1q = min((u32)(f1 * 65536.0f), 65535u);
    uint2 rec;
    rec.x = (u32)src | ((u32)p0 << 16) | ((u32)p1 << 19);
    rec.y = f0q | (f1q << 16);
    return rec;
}

// ---------------- bucket-sort CSR build (replaces hist+scan+scatter) ----------------

// Pass 1: per-block LDS histogram of bucket ids (dst>>7), one global atomic
// per (block, nonempty bucket) to reserve append ranges, then chunked record
// writes. Local dst (7 bits) packed into record bits 22..28 for pass 2.
__global__ __launch_bounds__(256) void bucket_scatter(
    const int* __restrict__ ei, const float* __restrict__ ps,
    u32* __restrict__ bcur, uint2* __restrict__ bucketed, int E, int NB)
{
    __shared__ u32 lhist[BK_MAXNB];
    __shared__ u32 lbase[BK_MAXNB];
    const int t = threadIdx.x;
    const int e0 = blockIdx.x * EDGES_PER_BLK;
    for (int k = t; k < NB; k += 256) lhist[k] = 0;
    __syncthreads();
    u32 pk[16];
#pragma unroll
    for (int r = 0; r < 16; ++r) {
        const int e = e0 + r * 256 + t;
        u32 v = 0u;
        if (e < E) {
            const int bkt = ei[E + e] >> BK_SHIFT;
            const u32 lr = atomicAdd(&lhist[bkt], 1u);   // lr < 4096
            v = ((u32)bkt << 13) | lr;
        }
        pk[r] = v;
    }
    __syncthreads();
    for (int k = t; k < NB; k += 256) {
        const u32 h = lhist[k];
        lbase[k] = h ? atomicAdd(&bcur[k], h) : 0u;
    }
    __syncthreads();
#pragma unroll
    for (int r = 0; r < 16; ++r) {
        const int e = e0 + r * 256 + t;
        if (e < E) {
            const u32 v = pk[r];
            const int bkt = (int)(v >> 13);
            const u32 lr = v & 0x1FFFu;
            u32 slot = lbase[bkt] + lr;
            if (slot >= BK_CAP) slot = BK_CAP - 1;       // safety clamp (never in practice)
            const int src = ei[e];
            const int dst = ei[E + e];
            uint2 rec = mkrec(src, ps[2 * e], ps[2 * e + 1]);
            rec.x |= (u32)(dst & (BK_W - 1)) << 22;
            bucketed[(size_t)bkt * BK_CAP + slot] = rec;
        }
    }
}

// Tiny scan over NB bucket counts -> exclusive bases.
__global__ __launch_bounds__(256) void bucket_bases(
    const u32* __restrict__ bcur, u32* __restrict__ bbase, int NB)
{
    __shared__ u32 tmp[BK_MAXNB];
    const int t = threadIdx.x;
    for (int k = t; k < NB; k += 256) tmp[k] = min(bcur[k], (u32)BK_CAP);
    __syncthreads();
    if (t == 0) {
        u32 run = 0;
        for (int k = 0; k < NB; ++k) { const u32 c = tmp[k]; tmp[k] = run; run += c; }
    }
    __syncthreads();
    for (int k = t; k < NB; k += 256) bbase[k] = tmp[k];
}

// Pass 2: one block per bucket. Count the bucket's 128 nodes, serial-scan,
// place records into an LDS buffer, stream out coalesced, and write cursor
// for the bucket's node range (cursor[N] falls out of the last bucket).
__global__ __launch_bounds__(256) void bucket_sort(
    const uint2* __restrict__ bucketed, const u32* __restrict__ bcur,
    const u32* __restrict__ bbase, uint2* __restrict__ sorted,
    u32* __restrict__ cursor, int N)
{
    __shared__ __align__(16) uint2 buf[BK_CAP];          // 40 KB
    __shared__ u32 lhist[BK_W + 1];
    __shared__ u32 lbase[BK_W + 1];
    const int b = blockIdx.x;
    const int t = threadIdx.x;
    const int cnt = (int)min(bcur[b], (u32)BK_CAP);
    const u32 gb = bbase[b];
    const uint2* __restrict__ in = bucketed + (size_t)b * BK_CAP;

    for (int k = t; k <= BK_W; k += 256) lhist[k] = 0;
    __syncthreads();
    for (int i = t; i < cnt; i += 256) {
        const u32 nl = (in[i].x >> 22) & (BK_W - 1);
        atomicAdd(&lhist[nl], 1u);
    }
    __syncthreads();
    if (t == 0) {
        u32 run = 0;
        for (int k = 0; k <= BK_W; ++k) { const u32 c = lhist[k]; lhist[k] = run; run += c; }
    }
    __syncthreads();
    for (int k = t; k <= BK_W; k += 256) lbase[k] = lhist[k];
    __syncthreads();
    // lhist now doubles as live per-node cursors (starting at base)
    for (int i = t; i < cnt; i += 256) {
        const uint2 r = in[i];
        const u32 nl = (r.x >> 22) & (BK_W - 1);
        const u32 p = atomicAdd(&lhist[nl], 1u);
        buf[p] = r;
    }
    __syncthreads();
    for (int i = t; i < cnt; i += 256) sorted[gb + i] = buf[i];
    for (int k = t; k <= BK_W; k += 256) {
        const int node = b * BK_W + k;
        if (node <= N) cursor[node] = gb + lbase[k];
    }
}

// ---------------- BARRIER-FREE gemm (wave-private staging) ----------------
// Each wave owns 16 output rows and its OWN double-buffered LDS (2 x 8 KB =
// one cell each). No __syncthreads anywhere: per-wave counted vmcnt orders
// staged loads; epilogue stores are NEVER drained. LDS = 64 KB -> 2 blocks/CU.
// Interleaved pair lines: line (p,d1) at d1*512 + p*128 holds dwords
// [L0 R0 L1 R1 ...]; cell d0>=1 stores uint2 {prev,cur} at pair d0-1, offset
// 8m. Root cell -> float4 into rootf. OOB rows clamp to N-1 and always store
// so vmcnt constants stay valid per wave.
__global__ __launch_bounds__(256) void gemm_nb(
    const float* __restrict__ X, const __hip_bfloat16* __restrict__ Wb,
    char* __restrict__ XK, float* __restrict__ rootf, int N)
{
    __shared__ __align__(16) char lds[4][2][CELL_BYTES];
    const int lane = threadIdx.x & 63;
    const int wv   = threadIdx.x >> 6;
    const int rb   = blockIdx.x * 64 + wv * 16;
    const int m    = lane & 15;
    const int quad = lane >> 4;
    const int Nm1  = N - 1;

    const int rowc = min(rb + m, Nm1);
    const float* __restrict__ xp = X + (size_t)rowc * CHANNELS + quad * 8;
    float af[16];
    *(float4*)(af)      = *(const float4*)(xp);
    *(float4*)(af + 4)  = *(const float4*)(xp + 4);
    *(float4*)(af + 8)  = *(const float4*)(xp + 32);
    *(float4*)(af + 12) = *(const float4*)(xp + 36);
    bf16x8 A0, A1;
#pragma unroll
    for (int j = 0; j < 8; ++j) { A0[j] = f2bf(af[j]); A1[j] = f2bf(af[8 + j]); }

    const int r0 = rb + quad * 4;
    const char* __restrict__ wbc = (const char*)Wb;
    char* const ldsw = &lds[wv][0][0];

    auto stage = [&](int c, int buf) {
        const char* gsrc = wbc + (size_t)c * CELL_BYTES + lane * 16;
        char* lb = ldsw + buf * CELL_BYTES;
#pragma unroll
        for (int k = 0; k < 8; ++k)
            async_copy16(gsrc + k * 1024, lb + k * 1024);
    };

    u32 prevp[4] = {0u, 0u, 0u, 0u};   // pending left-slot dwords (per row i)

    stage(0, 0);
    stage(1, 1);

    unrollg<0, NBLK>([&](auto icc) {
        constexpr int c = decltype(icc)::v;
        // wait for stage(c): allow everything issued after it to remain
        // in flight = stores(c-1) + (stage(c+1) if it exists).
        constexpr int NC = (c == 0) ? 8
                         : cell_stores(c - 1) + ((c + 1 < NBLK) ? 8 : 0);
        asm volatile("s_waitcnt vmcnt(%0)" :: "i"(NC) : "memory");

        const char* cb = ldsw + (c & 1) * CELL_BYTES + lane * 16;
        f32x4 acc0 = {0.f, 0.f, 0.f, 0.f};
        f32x4 acc1 = {0.f, 0.f, 0.f, 0.f};
        f32x4 acc2 = {0.f, 0.f, 0.f, 0.f};
        f32x4 acc3 = {0.f, 0.f, 0.f, 0.f};
        acc0 = __builtin_amdgcn_mfma_f32_16x16x32_bf16(A0, *(const bf16x8*)(cb),        acc0, 0, 0, 0);
        acc0 = __builtin_amdgcn_mfma_f32_16x16x32_bf16(A1, *(const bf16x8*)(cb + 1024), acc0, 0, 0, 0);
        acc1 = __builtin_amdgcn_mfma_f32_16x16x32_bf16(A0, *(const bf16x8*)(cb + 2048), acc1, 0, 0, 0);
        acc1 = __builtin_amdgcn_mfma_f32_16x16x32_bf16(A1, *(const bf16x8*)(cb + 3072), acc1, 0, 0, 0);
        acc2 = __builtin_amdgcn_mfma_f32_16x16x32_bf16(A0, *(const bf16x8*)(cb + 4096), acc2, 0, 0, 0);
        acc2 = __builtin_amdgcn_mfma_f32_16x16x32_bf16(A1, *(const bf16x8*)(cb + 5120), acc2, 0, 0, 0);
        acc3 = __builtin_amdgcn_mfma_f32_16x16x32_bf16(A0, *(const bf16x8*)(cb + 6144), acc3, 0, 0, 0);
        acc3 = __builtin_amdgcn_mfma_f32_16x16x32_bf16(A1, *(const bf16x8*)(cb + 7168), acc3, 0, 0, 0);

        if constexpr (c < KK) {
            constexpr int d1 = c / 5;
            constexpr int d0 = c % 5;
            u32 pk[4];
#pragma unroll
            for (int i = 0; i < 4; ++i) {
                u32 p = __builtin_amdgcn_cvt_pk_fp8_f32(acc0[i], acc1[i], 0u, false);
                p = __builtin_amdgcn_cvt_pk_fp8_f32(acc2[i], acc3[i], p, true);
                pk[i] = p;
            }
            if constexpr (d0 >= 1) {
#pragma unroll
                for (int i = 0; i < 4; ++i) {
                    const int r = min(r0 + i, Nm1);
                    *(uint2*)(XK + (size_t)r * ROWP
                              + (d1 * 512 + (d0 - 1) * 128) + 8 * m) =
                        make_uint2(prevp[i], pk[i]);
                }
            }
#pragma unroll
            for (int i = 0; i < 4; ++i) prevp[i] = pk[i];
        } else {
#pragma unroll
            for (int i = 0; i < 4; ++i) {
                const int r = min(r0 + i, Nm1);
                *(float4*)(rootf + (size_t)r * CHANNELS + 4 * m) =
                    make_float4(acc0[i], acc1[i], acc2[i], acc3[i]);
            }
        }
        if constexpr (c + 2 < NBLK) {
            asm volatile("s_waitcnt lgkmcnt(0)" ::: "memory");
            stage(c + 2, c & 1);       // refill the buffer just consumed
        }
    });
}

// ------------- unified agg: interleaved pair lines, 2 uint2 gathers/edge -------------
// Quarter q = lane>>4 handles edge i+q, sublane j = lane&15 handles channels
// 4j..4j+3. Line (p0,p1) at p1*512+p0*128: dword 2j = left cell, 2j+1 = right
// cell -> one uint2 at +8j; second line at +512. 4-deep record queue +
// 3-deep gather queue. relu selects L1/L2 epilogue. Blocks >= node_blocks run
// prep_w for the NEXT layer's weights. (Record bits 22+ carry bucket-local
// dst — masked off by the &0xffff / &7 extractions.)
__global__ __launch_bounds__(256) void agg_node_p(
    const uint2* __restrict__ sorted, const u32* __restrict__ cursor,
    const char* __restrict__ XK, const float* __restrict__ rootf,
    const float* __restrict__ bias, float* __restrict__ out, int N, int relu,
    int node_blocks, const float* __restrict__ Wsrc,
    const float* __restrict__ rootsrc, __hip_bfloat16* __restrict__ Wbdst)
{
    if ((int)blockIdx.x >= node_blocks) {
        // fused prep_w for the next layer (runs only in the L1 agg dispatch)
        int idx = ((int)blockIdx.x - node_blocks) * 256 + threadIdx.x;
        if (idx < NTILES * 2 * 64 * 8) {
            int j = idx & 7;
            int l = (idx >> 3) & 63;
            int q = (idx >> 9) & 1;
            int t = idx >> 10;
            int cell = t >> 2;
            int o    = 4 * (l & 15) + (t & 3);
            int k    = q * 32 + (l >> 4) * 8 + j;
            float s = (cell < KK) ? Wsrc[cell * 4096 + k * 64 + o] : rootsrc[k * 64 + o];
            ((unsigned short*)Wbdst)[idx] = (unsigned short)f2bf(s);
        }
        return;
    }
    const int lane = threadIdx.x & 63;
    const int n = blockIdx.x * 4 + (threadIdx.x >> 6);
    if (n >= N) return;
    const int q = lane >> 4, j = lane & 15;
    const int beg = (int)cursor[n];
    const int end = (int)cursor[n + 1];

    float m0 = -INFINITY, m1 = -INFINITY, m2 = -INFINITY, m3 = -INFINITY;
    if (beg < end) {
        const int last = end - 1;
#define GATHP(r, q0, q1)                                                       \
        {                                                                      \
            const char* b_ = XK + (size_t)((r).x & 0xffff) * ROWP + (j << 3);  \
            const int o_ = (((int)((r).x >> 16) & 7)                           \
                            + (((int)((r).x >> 19) & 7) << 2)) << 7;           \
            q0 = *(const uint2*)(b_ + o_);                                     \
            q1 = *(const uint2*)(b_ + o_ + 512);                               \
        }
        uint2 rA = sorted[min(beg + q,      last)];
        uint2 rB = sorted[min(beg + 4 + q,  last)];
        uint2 rC = sorted[min(beg + 8 + q,  last)];
        uint2 ga0, ga1, gb0, gb1, gc0, gc1;
        GATHP(rA, ga0, ga1)
        GATHP(rB, gb0, gb1)
        for (int i = beg; i < end; i += 4) {
            uint2 rD = sorted[min(i + 12 + q, last)];
            GATHP(rC, gc0, gc1)
            const float f0 = (float)(rA.y & 0xffff) * (1.0f / 65536.0f);
            const float f1 = (float)(rA.y >> 16)    * (1.0f / 65536.0f);
            const float w00 = (1.f - f0) * (1.f - f1);
            const float w10 = f0 * (1.f - f1);
            const float w01 = (1.f - f0) * f1;
            const float w11 = f0 * f1;
            f32x2 s01 = __builtin_amdgcn_cvt_pk_f32_fp8(ga0.x, false) * w00
                      + __builtin_amdgcn_cvt_pk_f32_fp8(ga0.y, false) * w10
                      + __builtin_amdgcn_cvt_pk_f32_fp8(ga1.x, false) * w01
                      + __builtin_amdgcn_cvt_pk_f32_fp8(ga1.y, false) * w11;
            f32x2 s23 = __builtin_amdgcn_cvt_pk_f32_fp8(ga0.x, true)  * w00
                      + __builtin_amdgcn_cvt_pk_f32_fp8(ga0.y, true)  * w10
                      + __builtin_amdgcn_cvt_pk_f32_fp8(ga1.x, true)  * w01
                      + __builtin_amdgcn_cvt_pk_f32_fp8(ga1.y, true)  * w11;
            m0 = fmaxf(m0, s01.x); m1 = fmaxf(m1, s01.y);
            m2 = fmaxf(m2, s23.x); m3 = fmaxf(m3, s23.y);
            rA = rB; rB = rC; rC = rD;
            ga0 = gb0; ga1 = gb1;
            gb0 = gc0; gb1 = gc1;
        }
#undef GATHP
    }
    m0 = fmaxf(m0, __shfl_xor(m0, 16, 64)); m0 = fmaxf(m0, __shfl_xor(m0, 32, 64));
    m1 = fmaxf(m1, __shfl_xor(m1, 16, 64)); m1 = fmaxf(m1, __shfl_xor(m1, 32, 64));
    m2 = fmaxf(m2, __shfl_xor(m2, 16, 64)); m2 = fmaxf(m2, __shfl_xor(m2, 32, 64));
    m3 = fmaxf(m3, __shfl_xor(m3, 16, 64)); m3 = fmaxf(m3, __shfl_xor(m3, 32, 64));
    const float a0 = isfinite(m0) ? m0 : 0.f;
    const float a1 = isfinite(m1) ? m1 : 0.f;
    const float a2 = isfinite(m2) ? m2 : 0.f;
    const float a3 = isfinite(m3) ? m3 : 0.f;

    const float4 rv = *(const float4*)(rootf + (size_t)n * CHANNELS + 4 * j);
    const float4 bv = *(const float4*)(bias + 4 * j);
    float r0 = a0 + rv.x + bv.x;
    float r1 = a1 + rv.y + bv.y;
    float r2 = a2 + rv.z + bv.z;
    float r3 = a3 + rv.w + bv.w;
    if (relu) {
        r0 = fmaxf(r0, 0.f); r1 = fmaxf(r1, 0.f);
        r2 = fmaxf(r2, 0.f); r3 = fmaxf(r3, 0.f);
    }
    if (q == 0)
        *(float4*)(out + (size_t)n * CHANNELS + 4 * j) = make_float4(r0, r1, r2, r3);
}

extern "C" void kernel_launch(void* const* d_in, const int* in_sizes, int n_in,
                              void* d_out, int out_size, void* d_ws, size_t ws_size,
                              hipStream_t stream) {
    const float* x     = (const float*)d_in[0];
    const int*   ei    = (const int*)d_in[1];
    const float* ps    = (const float*)d_in[2];
    const float* W1    = (const float*)d_in[3];
    const float* root1 = (const float*)d_in[4];
    const float* bias1 = (const float*)d_in[5];
    const float* W2    = (const float*)d_in[6];
    const float* root2 = (const float*)d_in[7];
    const float* bias2 = (const float*)d_in[8];
    float* out = (float*)d_out;

    const int N = in_sizes[0] / CHANNELS;
    const int E = in_sizes[1] / 2;
    const int NB = (N + BK_W - 1) / BK_W;       // 391 for N=50000

    // ---- workspace layout (~196 MB) ----
    char* ws = (char*)d_ws;
    char* xk = ws;                                                  // N*2560 fp8 pair-dup spline
    size_t off = (size_t)N * ROWP;
    float* h = (float*)(ws + off);                                  // 12.8 MB
    off += (size_t)N * CHANNELS * sizeof(float);
    float* rootf = (float*)(ws + off);                              // 12.8 MB (f32 root term)
    off += (size_t)N * CHANNELS * sizeof(float);
    uint2* sorted = (uint2*)(ws + off);                             // E*8 = 12.8 MB
    off += (size_t)E * sizeof(uint2);
    uint2* bucketed = (uint2*)(ws + off);                           // 512*5120*8 = 21 MB
    off += (size_t)BK_MAXNB * BK_CAP * sizeof(uint2);
    u32* bcur = (u32*)(ws + off);                                   // 2 KB
    off += (size_t)BK_MAXNB * 4;
    u32* bbase = (u32*)(ws + off);                                  // 2 KB
    off += (size_t)BK_MAXNB * 4;
    __hip_bfloat16* Wb = (__hip_bfloat16*)(ws + off);               // 213 KB
    off += (size_t)NTILES * 2 * 64 * 8 * 2;
    u32* cursor = (u32*)(ws + off);                                 // (N+1)*4
    off += ((size_t)N + 1) * 4;

    const int prep_blocks = (NTILES * 2 * 64 * 8 + 255) / 256;
    const int gemm_blocks = (N + 63) / 64;
    const int node_blocks = (N + 3) / 4;
    const int bscat_blocks = (E + EDGES_PER_BLK - 1) / EDGES_PER_BLK;

    // zero the bucket cursors (capture-safe async memset)
    hipMemsetAsync(bcur, 0, (size_t)BK_MAXNB * 4, stream);
    prep_w<<<prep_blocks, 256, 0, stream>>>(W1, root1, Wb);

    // CSR build: bucket scatter -> bases scan -> per-bucket sort
    bucket_scatter<<<bscat_blocks, 256, 0, stream>>>(ei, ps, bcur, bucketed, E, NB);
    bucket_bases<<<1, 256, 0, stream>>>(bcur, bbase, NB);
    bucket_sort<<<NB, 256, 0, stream>>>(bucketed, bcur, bbase, sorted, cursor, N);

    // L1 gemm — barrier-free wave-private pipeline
    gemm_nb<<<gemm_blocks, 256, 0, stream>>>(x, Wb, xk, rootf, N);

    // L1 agg || fused prep_w(W2) repack
    agg_node_p<<<node_blocks + prep_blocks, 256, 0, stream>>>(
        sorted, cursor, xk, rootf, bias1, h, N, 1, node_blocks, W2, root2, Wb);

    // ---- layer 2 (reuses sorted/cursor) ----
    gemm_nb<<<gemm_blocks, 256, 0, stream>>>(h, Wb, xk, rootf, N);
    agg_node_p<<<node_blocks, 256, 0, stream>>>(
        sorted, cursor, xk, rootf, bias2, out, N, 0, node_blocks, W2, root2, Wb);
}

// Round 14
// 349.917 us; speedup vs baseline: 1.3186x; 1.0468x over previous
//
#include <hip/hip_runtime.h>
#include <hip/hip_bf16.h>
#include <math.h>

#define CHANNELS 64
#define KK 25                   // 5x5 kernels
#define NBLK 26                 // 25 spline kernels + 1 root block
#define NCOL (NBLK * CHANNELS)  // 1664 columns of the fused GEMM
#define NTILES (NCOL / 16)      // 104 col-tiles of 16
#define ROWP 2560               // xk row stride: 5 d1-rows x 4 pairs x 128 B (interleaved pair-dup fp8)
#define HALF_BYTES 4096         // half-cell = 2 tiles x 2 KB
#define NHALF (2 * NBLK)        // 52 half-cells

// ---- bucket-sort CSR parameters ----
#define BK_SHIFT 7
#define BK_W 128                // dst values per bucket
#define BK_CAP 5120             // record capacity per bucket (mean ~4092, +16 sigma)
#define BK_MAXNB 512            // max buckets supported (N <= 65536)
#define EDGES_PER_BLK 4096      // bucket_scatter edges per block

typedef __attribute__((ext_vector_type(8))) short bf16x8;
typedef __attribute__((ext_vector_type(4))) float f32x4;
typedef __attribute__((ext_vector_type(2))) float f32x2;
typedef unsigned int u32;

// RNE float -> bf16 bits
__device__ __forceinline__ u32 f2bfu(float f) {
    u32 u = __float_as_uint(f);
    return (u + 0x7FFFu + ((u >> 16) & 1u)) >> 16;
}
__device__ __forceinline__ short f2bf(float f) { return (short)f2bfu(f); }

// async global->LDS, 16 B per lane (lds dest = wave-uniform base + lane*16)
__device__ __forceinline__ void async_copy16(const void* g, void* l) {
    __builtin_amdgcn_global_load_lds(
        (const __attribute__((address_space(1))) u32*)g,
        (__attribute__((address_space(3))) u32*)l, 16, 0, 0);
}

// compile-time unroll helper
template<int N> struct IC { static constexpr int v = N; };
template<int G, int GEND, class F>
__device__ __forceinline__ void unrollg(F f) {
    if constexpr (G < GEND) { f(IC<G>{}); unrollg<G + 1, GEND>(f); }
}

// epilogue stores issued per cell (uint2 pair stores; root cell = 4 float4)
__device__ constexpr int cell_stores(int c) {
    return (c < KK) ? (((c % 5) != 0) ? 4 : 0) : 4;
}

// ---------------- weight repack ----------------

// Repack [W | root] fp32 -> Wb bf16 in B-fragment order.
// CELL-PERMUTED columns: within cell (t>>2), tile a = t&3 carries channels
// 4c + a (c = tile column 0..15). After the 4 MFMAs of a cell, lane m holds
// channels 4m..4m+3 across its four accumulators -> packed dword stores.
__global__ __launch_bounds__(256) void prep_w(const float* __restrict__ W,
                                              const float* __restrict__ root,
                                              __hip_bfloat16* __restrict__ Wb) {
    int idx = blockIdx.x * 256 + threadIdx.x;   // 104*2*64*8 = 106496
    if (idx >= NTILES * 2 * 64 * 8) return;
    int j = idx & 7;
    int l = (idx >> 3) & 63;
    int q = (idx >> 9) & 1;
    int t = idx >> 10;
    int cell = t >> 2;
    int o    = 4 * (l & 15) + (t & 3);          // channel within the 64-block
    int k    = q * 32 + (l >> 4) * 8 + j;
    float src = (cell < KK) ? W[cell * 4096 + k * 64 + o] : root[k * 64 + o];
    ((unsigned short*)Wb)[idx] = (unsigned short)f2bf(src);
}

// Build one 8-B edge record: pair indices p0,p1 in [0,3], fracs f'=v-p in [0,1].
__device__ __forceinline__ uint2 mkrec(int src, float v0f, float v1f) {
    const float v0 = v0f * 4.0f, v1 = v1f * 4.0f;
    const int p0 = max(min((int)floorf(v0), 3), 0);
    const int p1 = max(min((int)floorf(v1), 3), 0);
    const float f0 = v0 - (float)p0;   // in [0,1]; ==1 only at the v=4 boundary
    const float f1 = v1 - (float)p1;
    const u32 f0q = min((u32)(f0 * 65536.0f), 65535u);
    const u32 f1q = min((u32)(f1 * 65536.0f), 65535u);
    uint2 rec;
    rec.x = (u32)src | ((u32)p0 << 16) | ((u32)p1 << 19);
    rec.y = f0q | (f1q << 16);
    return rec;
}

// ---------------- bucket-sort CSR build ----------------

// Pass 1 (single-read): per-block LDS histogram of bucket ids (dst>>7) with
// records built into REGISTERS during the same pass; one global atomic per
// (block, nonempty bucket) to reserve ranges; then register->global record
// writes. Local dst (7 bits) packed into record bits 22..28 for pass 2.
__global__ __launch_bounds__(256) void bucket_scatter(
    const int* __restrict__ ei, const float* __restrict__ ps,
    u32* __restrict__ bcur, uint2* __restrict__ bucketed, int E, int NB)
{
    __shared__ u32 lhist[BK_MAXNB];
    __shared__ u32 lbase[BK_MAXNB];
    const int t = threadIdx.x;
    const int e0 = blockIdx.x * EDGES_PER_BLK;
    for (int k = t; k < NB; k += 256) lhist[k] = 0;
    __syncthreads();
    u32 meta[16];
    uint2 recs[16];
#pragma unroll
    for (int r = 0; r < 16; ++r) {
        const int e = e0 + r * 256 + t;
        u32 v = 0u;
        uint2 rec = make_uint2(0u, 0u);
        if (e < E) {
            const int dst = ei[E + e];
            const int bkt = dst >> BK_SHIFT;
            const u32 lr = atomicAdd(&lhist[bkt], 1u);   // lr < 4096
            v = ((u32)bkt << 13) | lr;
            const float2 pp = *(const float2*)(ps + 2 * e);
            rec = mkrec(ei[e], pp.x, pp.y);
            rec.x |= (u32)(dst & (BK_W - 1)) << 22;
        }
        meta[r] = v;
        recs[r] = rec;
    }
    __syncthreads();
    for (int k = t; k < NB; k += 256) {
        const u32 h = lhist[k];
        lbase[k] = h ? atomicAdd(&bcur[k], h) : 0u;
    }
    __syncthreads();
#pragma unroll
    for (int r = 0; r < 16; ++r) {
        const int e = e0 + r * 256 + t;
        if (e < E) {
            const int bkt = (int)(meta[r] >> 13);
            u32 slot = lbase[bkt] + (meta[r] & 0x1FFFu);
            if (slot >= BK_CAP) slot = BK_CAP - 1;       // safety clamp (never in practice)
            bucketed[(size_t)bkt * BK_CAP + slot] = recs[r];
        }
    }
}

// Tiny scan over NB bucket counts -> exclusive bases.
__global__ __launch_bounds__(256) void bucket_bases(
    const u32* __restrict__ bcur, u32* __restrict__ bbase, int NB)
{
    __shared__ u32 tmp[BK_MAXNB];
    const int t = threadIdx.x;
    for (int k = t; k < NB; k += 256) tmp[k] = min(bcur[k], (u32)BK_CAP);
    __syncthreads();
    if (t == 0) {
        u32 run = 0;
        for (int k = 0; k < NB; ++k) { const u32 c = tmp[k]; tmp[k] = run; run += c; }
    }
    __syncthreads();
    for (int k = t; k < NB; k += 256) bbase[k] = tmp[k];
}

// Pass 2: one block per bucket. Count the bucket's 128 nodes, serial-scan,
// place records into an LDS buffer, stream out coalesced, and write cursor
// for the bucket's node range (cursor[N] falls out of the last bucket).
__global__ __launch_bounds__(256) void bucket_sort(
    const uint2* __restrict__ bucketed, const u32* __restrict__ bcur,
    const u32* __restrict__ bbase, uint2* __restrict__ sorted,
    u32* __restrict__ cursor, int N)
{
    __shared__ __align__(16) uint2 buf[BK_CAP];          // 40 KB
    __shared__ u32 lhist[BK_W + 1];
    __shared__ u32 lbase[BK_W + 1];
    const int b = blockIdx.x;
    const int t = threadIdx.x;
    const int cnt = (int)min(bcur[b], (u32)BK_CAP);
    const u32 gb = bbase[b];
    const uint2* __restrict__ in = bucketed + (size_t)b * BK_CAP;

    for (int k = t; k <= BK_W; k += 256) lhist[k] = 0;
    __syncthreads();
    for (int i = t; i < cnt; i += 256) {
        const u32 nl = (in[i].x >> 22) & (BK_W - 1);
        atomicAdd(&lhist[nl], 1u);
    }
    __syncthreads();
    if (t == 0) {
        u32 run = 0;
        for (int k = 0; k <= BK_W; ++k) { const u32 c = lhist[k]; lhist[k] = run; run += c; }
    }
    __syncthreads();
    for (int k = t; k <= BK_W; k += 256) lbase[k] = lhist[k];
    __syncthreads();
    // lhist now doubles as live per-node cursors (starting at base)
    for (int i = t; i < cnt; i += 256) {
        const uint2 r = in[i];
        const u32 nl = (r.x >> 22) & (BK_W - 1);
        const u32 p = atomicAdd(&lhist[nl], 1u);
        buf[p] = r;
    }
    __syncthreads();
    for (int i = t; i < cnt; i += 256) sorted[gb + i] = buf[i];
    for (int k = t; k <= BK_W; k += 256) {
        const int node = b * BK_W + k;
        if (node <= N) cursor[node] = gb + lbase[k];
    }
}

// ---------------- BARRIER-FREE gemm, half-cell staging (high occupancy) -------------
// Each wave owns 16 output rows and 2 x 4 KB wave-private buffers (one
// HALF-cell each: 2 tiles). 32 KB/block -> 5 blocks/CU, 20 waves/CU (vs 8 at
// cell granularity). No __syncthreads: per-wave counted vmcnt orders staged
// loads; epilogue stores never drained. Even half h=2c computes acc0/acc1;
// odd half computes acc2/acc3 + epilogue of cell c. Interleaved pair lines:
// cell d0>=1 stores uint2 {prev,cur} at pair d0-1, offset 8m; root cell ->
// float4 into rootf. OOB rows clamp to N-1 and always store so per-wave
// vmcnt constants stay valid.
__global__ __launch_bounds__(256) void gemm_nb(
    const float* __restrict__ X, const __hip_bfloat16* __restrict__ Wb,
    char* __restrict__ XK, float* __restrict__ rootf, int N)
{
    __shared__ __align__(16) char lds[4][2][HALF_BYTES];   // 32 KB
    const int lane = threadIdx.x & 63;
    const int wv   = threadIdx.x >> 6;
    const int rb   = blockIdx.x * 64 + wv * 16;
    const int m    = lane & 15;
    const int quad = lane >> 4;
    const int Nm1  = N - 1;

    const int rowc = min(rb + m, Nm1);
    const float* __restrict__ xp = X + (size_t)rowc * CHANNELS + quad * 8;
    float af[16];
    *(float4*)(af)      = *(const float4*)(xp);
    *(float4*)(af + 4)  = *(const float4*)(xp + 4);
    *(float4*)(af + 8)  = *(const float4*)(xp + 32);
    *(float4*)(af + 12) = *(const float4*)(xp + 36);
    bf16x8 A0, A1;
#pragma unroll
    for (int j = 0; j < 8; ++j) { A0[j] = f2bf(af[j]); A1[j] = f2bf(af[8 + j]); }

    const int r0 = rb + quad * 4;
    const char* __restrict__ wbc = (const char*)Wb;
    char* const ldsw = &lds[wv][0][0];

    auto stage = [&](int h, int buf) {     // one half-cell = 4 KB
        const char* gsrc = wbc + (size_t)h * HALF_BYTES + lane * 16;
        char* lb = ldsw + buf * HALF_BYTES;
#pragma unroll
        for (int k = 0; k < 4; ++k)
            async_copy16(gsrc + k * 1024, lb + k * 1024);
    };

    u32 prevp[4] = {0u, 0u, 0u, 0u};   // pending left-slot dwords (per row i)
    f32x4 acc0 = {0.f, 0.f, 0.f, 0.f};
    f32x4 acc1 = {0.f, 0.f, 0.f, 0.f};
    f32x4 acc2, acc3;

    stage(0, 0);
    stage(1, 1);

    unrollg<0, NHALF>([&](auto ich) {
        constexpr int h = decltype(ich)::v;
        // ops issued AFTER stage(h)'s loads (vmcnt retires in issue order):
        //   stage(h+1) [4 loads, if it exists] and — for even h>=2 — the
        //   epilogue stores of cell (h-2)/2 issued in iteration h-1.
        constexpr int NC = ((h + 1 < NHALF) ? 4 : 0)
                         + ((h % 2 == 0 && h >= 2) ? cell_stores((h - 2) / 2) : 0);
        asm volatile("s_waitcnt vmcnt(%0)" :: "i"(NC) : "memory");

        const char* cb = ldsw + (h & 1) * HALF_BYTES + lane * 16;
        if constexpr ((h & 1) == 0) {
            acc0 = {0.f, 0.f, 0.f, 0.f};
            acc1 = {0.f, 0.f, 0.f, 0.f};
            acc0 = __builtin_amdgcn_mfma_f32_16x16x32_bf16(A0, *(const bf16x8*)(cb),        acc0, 0, 0, 0);
            acc0 = __builtin_amdgcn_mfma_f32_16x16x32_bf16(A1, *(const bf16x8*)(cb + 1024), acc0, 0, 0, 0);
            acc1 = __builtin_amdgcn_mfma_f32_16x16x32_bf16(A0, *(const bf16x8*)(cb + 2048), acc1, 0, 0, 0);
            acc1 = __builtin_amdgcn_mfma_f32_16x16x32_bf16(A1, *(const bf16x8*)(cb + 3072), acc1, 0, 0, 0);
        } else {
            acc2 = {0.f, 0.f, 0.f, 0.f};
            acc3 = {0.f, 0.f, 0.f, 0.f};
            acc2 = __builtin_amdgcn_mfma_f32_16x16x32_bf16(A0, *(const bf16x8*)(cb),        acc2, 0, 0, 0);
            acc2 = __builtin_amdgcn_mfma_f32_16x16x32_bf16(A1, *(const bf16x8*)(cb + 1024), acc2, 0, 0, 0);
            acc3 = __builtin_amdgcn_mfma_f32_16x16x32_bf16(A0, *(const bf16x8*)(cb + 2048), acc3, 0, 0, 0);
            acc3 = __builtin_amdgcn_mfma_f32_16x16x32_bf16(A1, *(const bf16x8*)(cb + 3072), acc3, 0, 0, 0);

            constexpr int c = (h - 1) / 2;
            if constexpr (c < KK) {
                constexpr int d1 = c / 5;
                constexpr int d0 = c % 5;
                u32 pk[4];
#pragma unroll
                for (int i = 0; i < 4; ++i) {
                    u32 p = __builtin_amdgcn_cvt_pk_fp8_f32(acc0[i], acc1[i], 0u, false);
                    p = __builtin_amdgcn_cvt_pk_fp8_f32(acc2[i], acc3[i], p, true);
                    pk[i] = p;
                }
                if constexpr (d0 >= 1) {
#pragma unroll
                    for (int i = 0; i < 4; ++i) {
                        const int r = min(r0 + i, Nm1);
                        *(uint2*)(XK + (size_t)r * ROWP
                                  + (d1 * 512 + (d0 - 1) * 128) + 8 * m) =
                            make_uint2(prevp[i], pk[i]);
                    }
                }
#pragma unroll
                for (int i = 0; i < 4; ++i) prevp[i] = pk[i];
            } else {
#pragma unroll
                for (int i = 0; i < 4; ++i) {
                    const int r = min(r0 + i, Nm1);
                    *(float4*)(rootf + (size_t)r * CHANNELS + 4 * m) =
                        make_float4(acc0[i], acc1[i], acc2[i], acc3[i]);
                }
            }
        }
        if constexpr (h + 2 < NHALF) {
            // ds_reads of this buffer are complete (MFMA consumed them)
            asm volatile("s_waitcnt lgkmcnt(0)" ::: "memory");
            stage(h + 2, h & 1);       // refill the buffer just consumed
        }
    });
}

// ------------- unified agg: interleaved pair lines, 2 uint2 gathers/edge -------------
// Quarter q = lane>>4 handles edge i+q, sublane j = lane&15 handles channels
// 4j..4j+3. Line (p0,p1) at p1*512+p0*128: dword 2j = left cell, 2j+1 = right
// cell -> one uint2 at +8j; second line at +512. 4-deep record queue +
// 3-deep gather queue. relu selects L1/L2 epilogue. Blocks >= node_blocks run
// prep_w for the NEXT layer's weights. (Record bits 22+ carry bucket-local
// dst — masked off by the &0xffff / &7 extractions.)
__global__ __launch_bounds__(256) void agg_node_p(
    const uint2* __restrict__ sorted, const u32* __restrict__ cursor,
    const char* __restrict__ XK, const float* __restrict__ rootf,
    const float* __restrict__ bias, float* __restrict__ out, int N, int relu,
    int node_blocks, const float* __restrict__ Wsrc,
    const float* __restrict__ rootsrc, __hip_bfloat16* __restrict__ Wbdst)
{
    if ((int)blockIdx.x >= node_blocks) {
        // fused prep_w for the next layer (runs only in the L1 agg dispatch)
        int idx = ((int)blockIdx.x - node_blocks) * 256 + threadIdx.x;
        if (idx < NTILES * 2 * 64 * 8) {
            int j = idx & 7;
            int l = (idx >> 3) & 63;
            int q = (idx >> 9) & 1;
            int t = idx >> 10;
            int cell = t >> 2;
            int o    = 4 * (l & 15) + (t & 3);
            int k    = q * 32 + (l >> 4) * 8 + j;
            float s = (cell < KK) ? Wsrc[cell * 4096 + k * 64 + o] : rootsrc[k * 64 + o];
            ((unsigned short*)Wbdst)[idx] = (unsigned short)f2bf(s);
        }
        return;
    }
    const int lane = threadIdx.x & 63;
    const int n = blockIdx.x * 4 + (threadIdx.x >> 6);
    if (n >= N) return;
    const int q = lane >> 4, j = lane & 15;
    const int beg = (int)cursor[n];
    const int end = (int)cursor[n + 1];

    float m0 = -INFINITY, m1 = -INFINITY, m2 = -INFINITY, m3 = -INFINITY;
    if (beg < end) {
        const int last = end - 1;
#define GATHP(r, q0, q1)                                                       \
        {                                                                      \
            const char* b_ = XK + (size_t)((r).x & 0xffff) * ROWP + (j << 3);  \
            const int o_ = (((int)((r).x >> 16) & 7)                           \
                            + (((int)((r).x >> 19) & 7) << 2)) << 7;           \
            q0 = *(const uint2*)(b_ + o_);                                     \
            q1 = *(const uint2*)(b_ + o_ + 512);                               \
        }
        uint2 rA = sorted[min(beg + q,      last)];
        uint2 rB = sorted[min(beg + 4 + q,  last)];
        uint2 rC = sorted[min(beg + 8 + q,  last)];
        uint2 ga0, ga1, gb0, gb1, gc0, gc1;
        GATHP(rA, ga0, ga1)
        GATHP(rB, gb0, gb1)
        for (int i = beg; i < end; i += 4) {
            uint2 rD = sorted[min(i + 12 + q, last)];
            GATHP(rC, gc0, gc1)
            const float f0 = (float)(rA.y & 0xffff) * (1.0f / 65536.0f);
            const float f1 = (float)(rA.y >> 16)    * (1.0f / 65536.0f);
            const float w00 = (1.f - f0) * (1.f - f1);
            const float w10 = f0 * (1.f - f1);
            const float w01 = (1.f - f0) * f1;
            const float w11 = f0 * f1;
            f32x2 s01 = __builtin_amdgcn_cvt_pk_f32_fp8(ga0.x, false) * w00
                      + __builtin_amdgcn_cvt_pk_f32_fp8(ga0.y, false) * w10
                      + __builtin_amdgcn_cvt_pk_f32_fp8(ga1.x, false) * w01
                      + __builtin_amdgcn_cvt_pk_f32_fp8(ga1.y, false) * w11;
            f32x2 s23 = __builtin_amdgcn_cvt_pk_f32_fp8(ga0.x, true)  * w00
                      + __builtin_amdgcn_cvt_pk_f32_fp8(ga0.y, true)  * w10
                      + __builtin_amdgcn_cvt_pk_f32_fp8(ga1.x, true)  * w01
                      + __builtin_amdgcn_cvt_pk_f32_fp8(ga1.y, true)  * w11;
            m0 = fmaxf(m0, s01.x); m1 = fmaxf(m1, s01.y);
            m2 = fmaxf(m2, s23.x); m3 = fmaxf(m3, s23.y);
            rA = rB; rB = rC; rC = rD;
            ga0 = gb0; ga1 = gb1;
            gb0 = gc0; gb1 = gc1;
        }
#undef GATHP
    }
    m0 = fmaxf(m0, __shfl_xor(m0, 16, 64)); m0 = fmaxf(m0, __shfl_xor(m0, 32, 64));
    m1 = fmaxf(m1, __shfl_xor(m1, 16, 64)); m1 = fmaxf(m1, __shfl_xor(m1, 32, 64));
    m2 = fmaxf(m2, __shfl_xor(m2, 16, 64)); m2 = fmaxf(m2, __shfl_xor(m2, 32, 64));
    m3 = fmaxf(m3, __shfl_xor(m3, 16, 64)); m3 = fmaxf(m3, __shfl_xor(m3, 32, 64));
    const float a0 = isfinite(m0) ? m0 : 0.f;
    const float a1 = isfinite(m1) ? m1 : 0.f;
    const float a2 = isfinite(m2) ? m2 : 0.f;
    const float a3 = isfinite(m3) ? m3 : 0.f;

    const float4 rv = *(const float4*)(rootf + (size_t)n * CHANNELS + 4 * j);
    const float4 bv = *(const float4*)(bias + 4 * j);
    float r0 = a0 + rv.x + bv.x;
    float r1 = a1 + rv.y + bv.y;
    float r2 = a2 + rv.z + bv.z;
    float r3 = a3 + rv.w + bv.w;
    if (relu) {
        r0 = fmaxf(r0, 0.f); r1 = fmaxf(r1, 0.f);
        r2 = fmaxf(r2, 0.f); r3 = fmaxf(r3, 0.f);
    }
    if (q == 0)
        *(float4*)(out + (size_t)n * CHANNELS + 4 * j) = make_float4(r0, r1, r2, r3);
}

extern "C" void kernel_launch(void* const* d_in, const int* in_sizes, int n_in,
                              void* d_out, int out_size, void* d_ws, size_t ws_size,
                              hipStream_t stream) {
    const float* x     = (const float*)d_in[0];
    const int*   ei    = (const int*)d_in[1];
    const float* ps    = (const float*)d_in[2];
    const float* W1    = (const float*)d_in[3];
    const float* root1 = (const float*)d_in[4];
    const float* bias1 = (const float*)d_in[5];
    const float* W2    = (const float*)d_in[6];
    const float* root2 = (const float*)d_in[7];
    const float* bias2 = (const float*)d_in[8];
    float* out = (float*)d_out;

    const int N = in_sizes[0] / CHANNELS;
    const int E = in_sizes[1] / 2;
    const int NB = (N + BK_W - 1) / BK_W;       // 391 for N=50000

    // ---- workspace layout (~196 MB) ----
    char* ws = (char*)d_ws;
    char* xk = ws;                                                  // N*2560 fp8 pair-dup spline
    size_t off = (size_t)N * ROWP;
    float* h = (float*)(ws + off);                                  // 12.8 MB
    off += (size_t)N * CHANNELS * sizeof(float);
    float* rootf = (float*)(ws + off);                              // 12.8 MB (f32 root term)
    off += (size_t)N * CHANNELS * sizeof(float);
    uint2* sorted = (uint2*)(ws + off);                             // E*8 = 12.8 MB
    off += (size_t)E * sizeof(uint2);
    uint2* bucketed = (uint2*)(ws + off);                           // 512*5120*8 = 21 MB
    off += (size_t)BK_MAXNB * BK_CAP * sizeof(uint2);
    u32* bcur = (u32*)(ws + off);                                   // 2 KB
    off += (size_t)BK_MAXNB * 4;
    u32* bbase = (u32*)(ws + off);                                  // 2 KB
    off += (size_t)BK_MAXNB * 4;
    __hip_bfloat16* Wb = (__hip_bfloat16*)(ws + off);               // 213 KB
    off += (size_t)NTILES * 2 * 64 * 8 * 2;
    u32* cursor = (u32*)(ws + off);                                 // (N+1)*4
    off += ((size_t)N + 1) * 4;

    const int prep_blocks = (NTILES * 2 * 64 * 8 + 255) / 256;
    const int gemm_blocks = (N + 63) / 64;
    const int node_blocks = (N + 3) / 4;
    const int bscat_blocks = (E + EDGES_PER_BLK - 1) / EDGES_PER_BLK;

    // zero the bucket cursors (capture-safe async memset)
    hipMemsetAsync(bcur, 0, (size_t)BK_MAXNB * 4, stream);
    prep_w<<<prep_blocks, 256, 0, stream>>>(W1, root1, Wb);

    // CSR build: bucket scatter -> bases scan -> per-bucket sort
    bucket_scatter<<<bscat_blocks, 256, 0, stream>>>(ei, ps, bcur, bucketed, E, NB);
    bucket_bases<<<1, 256, 0, stream>>>(bcur, bbase, NB);
    bucket_sort<<<NB, 256, 0, stream>>>(bucketed, bcur, bbase, sorted, cursor, N);

    // L1 gemm — barrier-free wave-private half-cell pipeline
    gemm_nb<<<gemm_blocks, 256, 0, stream>>>(x, Wb, xk, rootf, N);

    // L1 agg || fused prep_w(W2) repack
    agg_node_p<<<node_blocks + prep_blocks, 256, 0, stream>>>(
        sorted, cursor, xk, rootf, bias1, h, N, 1, node_blocks, W2, root2, Wb);

    // ---- layer 2 (reuses sorted/cursor) ----
    gemm_nb<<<gemm_blocks, 256, 0, stream>>>(h, Wb, xk, rootf, N);
    agg_node_p<<<node_blocks, 256, 0, stream>>>(
        sorted, cursor, xk, rootf, bias2, out, N, 0, node_blocks, W2, root2, Wb);
}